// Round 5
// baseline (523.496 us; speedup 1.0000x reference)
//
#include <hip/hip_runtime.h>
#include <hip/hip_bf16.h>
#include <math.h>

#define D    256
#define BT   128     // chunk length == M tile
#define GN   128     // GEMM N tile per block (2 N-slices)
#define NSEG 32      // BT/4 segments per chunk (GEMM epilogue)

typedef unsigned short u16;
typedef unsigned int   u32;
typedef __attribute__((ext_vector_type(8))) short short8;   // 8 bf16 = 4 VGPRs
typedef __attribute__((ext_vector_type(4))) float floatx4;  // MFMA C/D frag

__device__ __forceinline__ float b2f(u16 v) {
    union { unsigned u; float f; } x; x.u = ((unsigned)v) << 16; return x.f;
}
__device__ __forceinline__ u16 f2b(float f) {
    union { unsigned u; float f; } x; x.f = f;
    unsigned lsb = (x.u >> 16) & 1;
    x.u += 0x7fffu + lsb;                 // RNE
    return (u16)(x.u >> 16);
}
__device__ __forceinline__ float sigm(float x) {
    return __builtin_amdgcn_rcpf(1.0f + __expf(-x));
}
__device__ __forceinline__ float tanhfast(float x) {
    return 1.0f - 2.0f * __builtin_amdgcn_rcpf(__expf(2.0f * x) + 1.0f);
}
__device__ __forceinline__ void async16(const u16* g, u16* l) {
    __builtin_amdgcn_global_load_lds(
        (const __attribute__((address_space(1))) unsigned int*)g,
        (__attribute__((address_space(3))) unsigned int*)l, 16, 0, 0);
}

// ---------------------------------------------------------------------------
// weight transpose + bf16 cast: wt[combo][m][n][k] = bf16(W[k][n])
// ---------------------------------------------------------------------------
__global__ __launch_bounds__(256) void wtrans_kernel(
    const float* __restrict__ Wz_f, const float* __restrict__ Wh_f,
    const float* __restrict__ Wz_b, const float* __restrict__ Wh_b,
    u16* __restrict__ wt)
{
    int id = blockIdx.x * 256 + threadIdx.x;       // < 5*3*65536
    int combo = id / (3 * 65536);
    int rem   = id % (3 * 65536);
    int m = rem >> 16;
    int e = rem & 65535;
    int k = e >> 8, n = e & 255;
    int l   = combo < 3 ? combo : combo - 3;
    int dir = combo < 3 ? 0 : 1;
    float v;
    if (m == 0) {
        const float* Wz = dir ? Wz_b : Wz_f;
        v = Wz[((size_t)l * D + k) * D + n];
    } else {
        const float* Wh = dir ? Wh_b : Wh_f;
        int kk = (m == 2) ? (k + D) : k;
        v = Wh[((size_t)l * 2 * D + kk) * D + n];
    }
    wt[(size_t)combo * 3 * 65536 + (size_t)m * 65536 + (size_t)n * D + k] = f2b(v);
}

// ---------------------------------------------------------------------------
// prep: xb = bf16(x), q broadcast, xq = bf16(x*qbf)
// ---------------------------------------------------------------------------
__global__ __launch_bounds__(256) void prep0_kernel(
    const float* __restrict__ story, const float* __restrict__ question,
    u16* __restrict__ xb, u16* __restrict__ q, u16* __restrict__ xq)
{
    long id = (long)blockIdx.x * 256 + threadIdx.x;
    long row = id >> 5;
    int  d0  = (int)(id & 31) * 8;
    const float* xp = story + row * D + d0;
    float4 xa = *(const float4*)xp;
    float4 xc = *(const float4*)(xp + 4);
    float xv[8] = {xa.x, xa.y, xa.z, xa.w, xc.x, xc.y, xc.z, xc.w};
    short8 xs, qs, xqs;
    #pragma unroll
    for (int i = 0; i < 8; ++i) {
        u16 qb = f2b(question[d0 + i]);
        xs[i]  = (short)f2b(xv[i]);
        qs[i]  = (short)qb;
        xqs[i] = (short)f2b(xv[i] * b2f(qb));
    }
    long o = id * 8;
    *(short8*)(xb + o) = xs;
    *(short8*)(q  + o) = qs;
    *(short8*)(xq + o) = xqs;
}

// ---------------------------------------------------------------------------
// LDS stage layout (GEMM): full double-buffer, 2 x 48 KB = 96 KB
// ---------------------------------------------------------------------------
struct StageS {
    u16 ax [BT * 32]; u16 aq [BT * 32]; u16 axq[BT * 32];   // 8KB each
    u16 bz_[GN * 32]; u16 bx_[GN * 32]; u16 bq_[GN * 32];   // 8KB each
};
struct StageD { StageS buf[2]; };                             // 96KB
struct EpiP { float segA[NSEG][GN]; float segB[NSEG][GN]; };  // 32KB
union __align__(16) SharedP { StageD st; EpiP ep; };

// ---------------------------------------------------------------------------
// shared GEMM body (512 threads / 8 waves, 128x128 tile, 64x32 wave tile):
// T3 minimum 2-phase pipeline: STAGE(k+1) issued BEFORE compute(k); the
// single trailing __syncthreads (vmcnt/lgkm drain) lands after ~500+ cyc
// of ds_read+MFMA, hiding the staging latency. 1 block/CU (96KB LDS).
// Epilogue writes prefix-composed (Aprod_t, hloc_t) packed bf16 pairs.
// ---------------------------------------------------------------------------
__device__ __forceinline__ void gemm_body(
    SharedP& sh, int tid, int c, int n0,
    const u16* xbg, const u16* qg, const u16* xqg, const u16* wt,
    const float* bz, const float* bh,
    float* aggA, float* aggB, u32* abg, int FWD)
{
    const int t0   = c * BT;
    const int lane = tid & 63, w = tid >> 6;    // 8 waves
    const int wr = w & 1, wc = w >> 1;          // row half / col quarter
    const int lr   = lane & 15, quad = lane >> 4;

    const int swA   = (quad ^ ((lr >> 1) & 3)) * 8;
    const int offA0 = (wr * 64 + lr) * 32 + swA;
    const int offB0 = (wc * 32 + lr) * 32 + swA;

    floatx4 accz[4][2], acch[4][2];
    #pragma unroll
    for (int rt = 0; rt < 4; ++rt)
        #pragma unroll
        for (int ct = 0; ct < 2; ++ct) {
            accz[rt][ct] = (floatx4){0.f,0.f,0.f,0.f};
            acch[rt][ct] = (floatx4){0.f,0.f,0.f,0.f};
        }

    const int lb = (tid & ~63) * 8;             // wave-uniform LDS base (u16)

    // staging addresses: 512 threads cover 128 rows x 4 swizzled 16B slots
    const int arow = tid >> 2;
    const int agg_ = (tid & 3) ^ ((arow >> 1) & 3);
    const size_t goA = (size_t)(t0 + arow) * D + agg_ * 8;
    const size_t goB = (size_t)(n0 + arow) * D + agg_ * 8;
    const u16* pax  = xbg + goA;
    const u16* paq  = qg  + goA;
    const u16* paxq = xqg + goA;
    const u16* pbz  = wt + goB;
    const u16* pbx  = wt + 65536  + goB;
    const u16* pbq  = wt + 131072 + goB;

    auto stage = [&](StageS& b, int k0) {
        async16(pax  + k0, b.ax  + lb);
        async16(paq  + k0, b.aq  + lb);
        async16(paxq + k0, b.axq + lb);
        async16(pbz  + k0, b.bz_ + lb);
        async16(pbx  + k0, b.bx_ + lb);
        async16(pbq  + k0, b.bq_ + lb);
    };

    // prologue: stage k=0, drain once
    stage(sh.st.buf[0], 0);
    __syncthreads();

    #pragma unroll
    for (int kk = 0; kk < 8; ++kk) {
        // issue next-tile loads FIRST (they drain at this iteration's barrier)
        if (kk < 7) stage(sh.st.buf[(kk + 1) & 1], (kk + 1) * 32);

        const StageS& S = sh.st.buf[kk & 1];
        short8 vz[2], vx[2], vq[2];
        #pragma unroll
        for (int ct = 0; ct < 2; ++ct) {
            vz[ct] = *(const short8*)(S.bz_ + offB0 + ct * 512);
            vx[ct] = *(const short8*)(S.bx_ + offB0 + ct * 512);
            vq[ct] = *(const short8*)(S.bq_ + offB0 + ct * 512);
        }
        #pragma unroll
        for (int rt = 0; rt < 4; ++rt) {
            short8 fxq = *(const short8*)(S.axq + offA0 + rt * 512);
            short8 fx  = *(const short8*)(S.ax  + offA0 + rt * 512);
            short8 fq  = *(const short8*)(S.aq  + offA0 + rt * 512);
            #pragma unroll
            for (int ct = 0; ct < 2; ++ct) {
                accz[rt][ct] = __builtin_amdgcn_mfma_f32_16x16x32_bf16(fxq, vz[ct], accz[rt][ct], 0, 0, 0);
                acch[rt][ct] = __builtin_amdgcn_mfma_f32_16x16x32_bf16(fx , vx[ct], acch[rt][ct], 0, 0, 0);
                acch[rt][ct] = __builtin_amdgcn_mfma_f32_16x16x32_bf16(fq , vq[ct], acch[rt][ct], 0, 0, 0);
            }
        }
        __syncthreads();   // drains vmcnt (stage k+1 ready) + lgkm (reads done)
    }

    // ---- gate epilogue (C/D: col = lr, rows = quad*4 + r) ----
    float bzn[2], bhn[2];
    #pragma unroll
    for (int ct = 0; ct < 2; ++ct) {
        int n = n0 + wc * 32 + ct * 16 + lr;
        bzn[ct] = bz[n]; bhn[ct] = bh[n];
    }
    float av[4][2][4], bvv[4][2][4];
    #pragma unroll
    for (int rt = 0; rt < 4; ++rt) {
        #pragma unroll
        for (int ct = 0; ct < 2; ++ct) {
            #pragma unroll
            for (int r = 0; r < 4; ++r) {
                float z  = sigm(accz[rt][ct][r] + bzn[ct]);
                float ht = tanhfast(acch[rt][ct][r] + bhn[ct]);
                av[rt][ct][r]  = 1.0f - z;
                bvv[rt][ct][r] = z * ht;
            }
            float A = 1.f, B = 0.f;
            if (FWD) {
                #pragma unroll
                for (int r = 0; r < 4; ++r) { A = av[rt][ct][r] * A; B = fmaf(av[rt][ct][r], B, bvv[rt][ct][r]); }
            } else {
                #pragma unroll
                for (int r = 3; r >= 0; --r) { A = av[rt][ct][r] * A; B = fmaf(av[rt][ct][r], B, bvv[rt][ct][r]); }
            }
            int seg = wr * 16 + rt * 4 + quad;       // = row/4
            int col = wc * 32 + ct * 16 + lr;
            sh.ep.segA[seg][col] = A;
            sh.ep.segB[seg][col] = B;
        }
    }
    __syncthreads();

    // in-place exclusive segment prefix (direction-ordered);
    // final running pair = chunk aggregate
    if (tid < GN) {
        float A = 1.f, B = 0.f;
        if (FWD) {
            #pragma unroll
            for (int sg = 0; sg < NSEG; ++sg) {
                float a = sh.ep.segA[sg][tid], b = sh.ep.segB[sg][tid];
                sh.ep.segA[sg][tid] = A; sh.ep.segB[sg][tid] = B;
                A = a * A; B = fmaf(a, B, b);
            }
        } else {
            #pragma unroll
            for (int sg = NSEG - 1; sg >= 0; --sg) {
                float a = sh.ep.segA[sg][tid], b = sh.ep.segB[sg][tid];
                sh.ep.segA[sg][tid] = A; sh.ep.segB[sg][tid] = B;
                A = a * A; B = fmaf(a, B, b);
            }
        }
        aggA[(size_t)c * D + n0 + tid] = A;
        aggB[(size_t)c * D + n0 + tid] = B;
    }

    if (abg) {
        __syncthreads();
        #pragma unroll
        for (int rt = 0; rt < 4; ++rt) {
            #pragma unroll
            for (int ct = 0; ct < 2; ++ct) {
                int seg = wr * 16 + rt * 4 + quad;
                int col = wc * 32 + ct * 16 + lr;
                float Pa = sh.ep.segA[seg][col];
                float Pb = sh.ep.segB[seg][col];
                size_t base = (size_t)(t0 + wr * 64 + rt * 16 + quad * 4) * D + n0 + col;
                if (FWD) {
                    #pragma unroll
                    for (int r = 0; r < 4; ++r) {
                        Pa = av[rt][ct][r] * Pa;
                        Pb = fmaf(av[rt][ct][r], Pb, bvv[rt][ct][r]);
                        abg[base + (size_t)r * D] = (u32)f2b(Pa) | ((u32)f2b(Pb) << 16);
                    }
                } else {
                    #pragma unroll
                    for (int r = 3; r >= 0; --r) {
                        Pa = av[rt][ct][r] * Pa;
                        Pb = fmaf(av[rt][ct][r], Pb, bvv[rt][ct][r]);
                        abg[base + (size_t)r * D] = (u32)f2b(Pa) | ((u32)f2b(Pb) << 16);
                    }
                }
            }
        }
    }
}

// single-direction GEMM (layer 2 fwd; plan P). grid = NCH*2 = 1024.
template<int FWD, int ABOUT>
__global__ __launch_bounds__(512, 2) void qrn_g5(
    const u16* __restrict__ xbg, const u16* __restrict__ qg,
    const u16* __restrict__ xqg, const u16* __restrict__ wt,
    const float* __restrict__ bz, const float* __restrict__ bh,
    float* __restrict__ aggA, float* __restrict__ aggB,
    u32* __restrict__ abg)
{
    __shared__ SharedP sh;
    const int tid  = threadIdx.x;
    const int bid  = (int)blockIdx.x;
    const int gidx = (bid & 7) * 128 + (bid >> 3);   // XCD-contiguous, bijective
    gemm_body(sh, tid, gidx >> 1, (gidx & 1) * GN,
              xbg, qg, xqg, wt, bz, bh, aggA, aggB, ABOUT ? abg : nullptr, FWD);
}

// combined fwd+bwd GEMM: blocks [0,1024) = fwd, [1024,2048) = bwd.
__global__ __launch_bounds__(512, 2) void qrn_gboth(
    const u16* __restrict__ xbg, const u16* __restrict__ qg,
    const u16* __restrict__ xqg,
    const u16* __restrict__ wtF, const u16* __restrict__ wtB,
    const float* __restrict__ bzf, const float* __restrict__ bhf,
    const float* __restrict__ bzb, const float* __restrict__ bhb,
    float* __restrict__ aggAf, float* __restrict__ aggBf,
    float* __restrict__ aggAb, float* __restrict__ aggBb,
    u32* __restrict__ abf, u32* __restrict__ abb)
{
    __shared__ SharedP sh;
    const int tid  = threadIdx.x;
    const int half = (int)blockIdx.x >> 10;       // 0=fwd, 1=bwd
    const int bid  = (int)blockIdx.x & 1023;
    const int gidx = (bid & 7) * 128 + (bid >> 3);
    gemm_body(sh, tid, gidx >> 1, (gidx & 1) * GN,
              xbg, qg, xqg,
              half ? wtB : wtF,
              half ? bzb : bzf, half ? bhb : bhf,
              half ? aggAb : aggAf, half ? aggBb : aggBf,
              half ? abb : abf, half ? 0 : 1);
}

// ===========================================================================
// elementwise replay: ab holds (Aprod_t, hloc_t) packed bf16.
// h_t = Aprod_t * hinit[chunk] + hloc_t. Pure streaming, vec8.
// ===========================================================================
__global__ __launch_bounds__(256) void replay2_fb(
    const u32* __restrict__ abf, const u32* __restrict__ abb,
    const float* __restrict__ hinif, const float* __restrict__ hinib,
    const u16* __restrict__ xb, u16* __restrict__ qout, u16* __restrict__ xq,
    int total8)
{
    for (int id = (int)blockIdx.x * 256 + (int)threadIdx.x; id < total8;
         id += (int)gridDim.x * 256) {
        int t  = id >> 5;
        int n0 = (id & 31) * 8;
        int c  = t >> 7;
        size_t o  = (size_t)t * D + n0;
        size_t hc = (size_t)c * D + n0;
        uint4 f0 = *(const uint4*)(abf + o);
        uint4 f1 = *(const uint4*)(abf + o + 4);
        uint4 g0 = *(const uint4*)(abb + o);
        uint4 g1 = *(const uint4*)(abb + o + 4);
        float4 hf0 = *(const float4*)(hinif + hc);
        float4 hf1 = *(const float4*)(hinif + hc + 4);
        float4 hb0 = *(const float4*)(hinib + hc);
        float4 hb1 = *(const float4*)(hinib + hc + 4);
        short8 xv = *(const short8*)(xb + o);
        u32 fa[8] = {f0.x, f0.y, f0.z, f0.w, f1.x, f1.y, f1.z, f1.w};
        u32 ga[8] = {g0.x, g0.y, g0.z, g0.w, g1.x, g1.y, g1.z, g1.w};
        float hfv[8] = {hf0.x, hf0.y, hf0.z, hf0.w, hf1.x, hf1.y, hf1.z, hf1.w};
        float hbv[8] = {hb0.x, hb0.y, hb0.z, hb0.w, hb1.x, hb1.y, hb1.z, hb1.w};
        short8 qs, xqs;
        #pragma unroll
        for (int i = 0; i < 8; ++i) {
            float hF = fmaf(b2f((u16)(fa[i] & 0xffff)), hfv[i], b2f((u16)(fa[i] >> 16)));
            float hB = fmaf(b2f((u16)(ga[i] & 0xffff)), hbv[i], b2f((u16)(ga[i] >> 16)));
            u16 qb = f2b(hF + hB);
            qs[i]  = (short)qb;
            xqs[i] = (short)f2b(b2f((u16)xv[i]) * b2f(qb));
        }
        *(short8*)(qout + o) = qs;
        *(short8*)(xq + o)   = xqs;
    }
}

// plan-P fallback replays (elementwise, same prefix semantics)
__global__ __launch_bounds__(256) void replay2_f(
    const u32* __restrict__ abg, const float* __restrict__ hini,
    u16* __restrict__ qout, int total8)
{
    for (int id = (int)blockIdx.x * 256 + (int)threadIdx.x; id < total8;
         id += (int)gridDim.x * 256) {
        int t  = id >> 5;
        int n0 = (id & 31) * 8;
        int c  = t >> 7;
        size_t o  = (size_t)t * D + n0;
        size_t hc = (size_t)c * D + n0;
        uint4 f0 = *(const uint4*)(abg + o);
        uint4 f1 = *(const uint4*)(abg + o + 4);
        float4 hf0 = *(const float4*)(hini + hc);
        float4 hf1 = *(const float4*)(hini + hc + 4);
        u32 fa[8] = {f0.x, f0.y, f0.z, f0.w, f1.x, f1.y, f1.z, f1.w};
        float hfv[8] = {hf0.x, hf0.y, hf0.z, hf0.w, hf1.x, hf1.y, hf1.z, hf1.w};
        short8 qs;
        #pragma unroll
        for (int i = 0; i < 8; ++i) {
            float hF = fmaf(b2f((u16)(fa[i] & 0xffff)), hfv[i], b2f((u16)(fa[i] >> 16)));
            qs[i] = (short)f2b(hF);
        }
        *(short8*)(qout + o) = qs;
    }
}

__global__ __launch_bounds__(256) void replay2_b(
    const u32* __restrict__ abg, const float* __restrict__ hini,
    const u16* __restrict__ xb, u16* __restrict__ qout, u16* __restrict__ xq,
    int total8)
{
    for (int id = (int)blockIdx.x * 256 + (int)threadIdx.x; id < total8;
         id += (int)gridDim.x * 256) {
        int t  = id >> 5;
        int n0 = (id & 31) * 8;
        int c  = t >> 7;
        size_t o  = (size_t)t * D + n0;
        size_t hc = (size_t)c * D + n0;
        uint4 g0 = *(const uint4*)(abg + o);
        uint4 g1 = *(const uint4*)(abg + o + 4);
        float4 hb0 = *(const float4*)(hini + hc);
        float4 hb1 = *(const float4*)(hini + hc + 4);
        short8 qold = *(const short8*)(qout + o);
        short8 xv   = *(const short8*)(xb + o);
        u32 ga[8] = {g0.x, g0.y, g0.z, g0.w, g1.x, g1.y, g1.z, g1.w};
        float hbv[8] = {hb0.x, hb0.y, hb0.z, hb0.w, hb1.x, hb1.y, hb1.z, hb1.w};
        short8 qs, xqs;
        #pragma unroll
        for (int i = 0; i < 8; ++i) {
            float hB = fmaf(b2f((u16)(ga[i] & 0xffff)), hbv[i], b2f((u16)(ga[i] >> 16)));
            float qn = b2f((u16)qold[i]) + hB;
            u16 qb = f2b(qn);
            qs[i]  = (short)qb;
            xqs[i] = (short)f2b(b2f((u16)xv[i]) * b2f(qb));
        }
        *(short8*)(qout + o) = qs;
        *(short8*)(xq + o)   = xqs;
    }
}

// ---------------------------------------------------------------------------
// inter-chunk scans
// ---------------------------------------------------------------------------
__device__ __forceinline__ void scan_body(
    const float* aggA, const float* aggB, float* hinit, float* out_final,
    int fwd, int nch, int n, int tid)
{
    __shared__ float sA[256], sB[256];
    const int per = nch >> 8;
    float lA[4], lB[4];
    float A = 1.f, B = 0.f;
    for (int j = 0; j < per; ++j) {
        int pidx = tid * per + j;
        int c = fwd ? pidx : (nch - 1 - pidx);
        float a = aggA[(size_t)c * D + n];
        float b = aggB[(size_t)c * D + n];
        lA[j] = a; lB[j] = b;
        A = a * A;
        B = fmaf(a, B, b);
    }
    sA[tid] = A; sB[tid] = B;
    __syncthreads();
    for (int off = 1; off < 256; off <<= 1) {
        float pA = 1.f, pB = 0.f;
        if (tid >= off) { pA = sA[tid - off]; pB = sB[tid - off]; }
        __syncthreads();
        if (tid >= off) {
            float cA = sA[tid], cB = sB[tid];
            sA[tid] = pA * cA;
            sB[tid] = fmaf(cA, pB, cB);
        }
        __syncthreads();
    }
    float eB = (tid > 0) ? sB[tid - 1] : 0.f;
    for (int j = 0; j < per; ++j) {
        int pidx = tid * per + j;
        int c = fwd ? pidx : (nch - 1 - pidx);
        hinit[(size_t)c * D + n] = eB;
        eB = fmaf(lA[j], eB, lB[j]);
    }
    if (out_final != nullptr && tid == 0) out_final[n] = sB[255];
}

__global__ __launch_bounds__(256) void scan_p2_kernel(
    const float* __restrict__ aggA, const float* __restrict__ aggB,
    float* __restrict__ hinit, float* __restrict__ out_final, int fwd, int nch)
{
    scan_body(aggA, aggB, hinit, out_final, fwd, nch, blockIdx.x, threadIdx.x);
}

__global__ __launch_bounds__(256) void scan_dual_kernel(
    const float* __restrict__ aggAf, const float* __restrict__ aggBf, float* __restrict__ hf,
    const float* __restrict__ aggAb, const float* __restrict__ aggBb, float* __restrict__ hb,
    int nch)
{
    int b = blockIdx.x;
    int fwd = (b < D) ? 1 : 0;
    int n = fwd ? b : (b - D);
    scan_body(fwd ? aggAf : aggAb, fwd ? aggBf : aggBb,
              fwd ? hf : hb, nullptr, fwd, nch, n, threadIdx.x);
}

// ---------------------------------------------------------------------------
extern "C" void kernel_launch(void* const* d_in, const int* in_sizes, int n_in,
                              void* d_out, int out_size, void* d_ws, size_t ws_size,
                              hipStream_t stream) {
    const float* story    = (const float*)d_in[0];
    const float* question = (const float*)d_in[1];
    const float* Wz_f = (const float*)d_in[2];
    const float* bz_f = (const float*)d_in[3];
    const float* Wh_f = (const float*)d_in[4];
    const float* bh_f = (const float*)d_in[5];
    const float* Wz_b = (const float*)d_in[6];
    const float* bz_b = (const float*)d_in[7];
    const float* Wh_b = (const float*)d_in[8];
    const float* bh_b = (const float*)d_in[9];

    const int T    = in_sizes[0] / D;            // 65536
    const int NCH  = T / BT;                     // 512
    const size_t TD = (size_t)T * D;
    const size_t WTE = 5 * 3 * 65536;
    const int total8 = T * 32;                   // TD/8

    // plan F: xb,q,xq (bf16) + wt + abf,abb (u32) + 4 agg arrays  (~231 MB)
    const size_t needF = 3 * TD * 2 + WTE * 2 + 2 * TD * 4
                       + (size_t)4 * NCH * D * 4 + 4096;
    const bool planF = ws_size >= needF;

    dim3 blk(256);
    dim3 gblk(512);                              // 8 waves, 64x32 wave tile
    dim3 gGrid((unsigned)(NCH * 2));             // 1024 (one dir, GN=128)
    dim3 g2Grid((unsigned)(NCH * 4));            // 2048 (both dirs)
    dim3 rGrid(2048);                            // replay grid-stride
    dim3 pGrid((unsigned)(TD / 8 / 256));

    if (planF) {
        u16* xb = (u16*)d_ws;
        u16* q  = xb + TD;
        u16* xq = q  + TD;
        u16* wt = xq + TD;
        u32* abf = (u32*)(wt + WTE);
        u32* abb = abf + TD;
        float* aggAf = (float*)(abb + TD);
        float* aggBf = aggAf + (size_t)NCH * D;
        float* aggAb = aggBf + (size_t)NCH * D;
        float* aggBb = aggAb + (size_t)NCH * D;
        float* hinif = aggBf;                    // alias (safe)
        float* hinib = aggBb;                    // alias (safe)

        wtrans_kernel<<<dim3(5 * 3 * 65536 / 256), blk, 0, stream>>>(
            Wz_f, Wh_f, Wz_b, Wh_b, wt);
        prep0_kernel<<<pGrid, blk, 0, stream>>>(story, question, xb, q, xq);

        for (int l = 0; l < 3; ++l) {
            const u16*   wtf = wt + (size_t)l * 3 * 65536;
            const float* bzf = bz_f + (size_t)l * D;
            const float* bhf = bh_f + (size_t)l * D;

            if (l == 2) {
                qrn_g5<1,0><<<gGrid, gblk, 0, stream>>>(
                    xb, q, xq, wtf, bzf, bhf, aggAf, aggBf, nullptr);
                scan_p2_kernel<<<dim3(D), blk, 0, stream>>>(
                    aggAf, aggBf, hinif, (float*)d_out, 1, NCH);
                break;
            }
            const u16*   wtb = wt + (size_t)(3 + l) * 3 * 65536;
            const float* bzb = bz_b + (size_t)l * D;
            const float* bhb = bh_b + (size_t)l * D;

            qrn_gboth<<<g2Grid, gblk, 0, stream>>>(
                xb, q, xq, wtf, wtb, bzf, bhf, bzb, bhb,
                aggAf, aggBf, aggAb, aggBb, abf, abb);
            scan_dual_kernel<<<dim3(2 * D), blk, 0, stream>>>(
                aggAf, aggBf, hinif, aggAb, aggBb, hinib, NCH);
            replay2_fb<<<rGrid, blk, 0, stream>>>(
                abf, abb, hinif, hinib, xb, q, xq, total8);
        }
    } else {
        // ---------------- plan P fallback ----------------
        u16* xb = (u16*)d_ws;
        u16* qA = xb + TD;
        u16* qB = qA + TD;
        u16* xq = qB + TD;
        u16* wt = xq + TD;
        u32*   ab   = (u32*)(wt + WTE);
        float* aggA = (float*)(ab + TD);
        float* aggB = aggA + (size_t)NCH * D;
        float* hini = aggB;

        wtrans_kernel<<<dim3(5 * 3 * 65536 / 256), blk, 0, stream>>>(
            Wz_f, Wh_f, Wz_b, Wh_b, wt);
        prep0_kernel<<<pGrid, blk, 0, stream>>>(story, question, xb, qA, xq);

        const u16* qcur  = qA;
        u16*       qnext = qB;

        for (int l = 0; l < 3; ++l) {
            const u16*   wtf = wt + (size_t)l * 3 * 65536;
            const float* bzf = bz_f + (size_t)l * D;
            const float* bhf = bh_f + (size_t)l * D;

            if (l == 2) {
                qrn_g5<1,0><<<gGrid, gblk, 0, stream>>>(
                    xb, qcur, xq, wtf, bzf, bhf, aggA, aggB, nullptr);
                scan_p2_kernel<<<dim3(D), blk, 0, stream>>>(
                    aggA, aggB, hini, (float*)d_out, 1, NCH);
                break;
            }
            const u16*   wtb = wt + (size_t)(3 + l) * 3 * 65536;
            const float* bzb = bz_b + (size_t)l * D;
            const float* bhb = bh_b + (size_t)l * D;

            qrn_g5<1,1><<<gGrid, gblk, 0, stream>>>(
                xb, qcur, xq, wtf, bzf, bhf, aggA, aggB, ab);
            scan_p2_kernel<<<dim3(D), blk, 0, stream>>>(aggA, aggB, hini, nullptr, 1, NCH);
            replay2_f<<<rGrid, blk, 0, stream>>>(ab, hini, qnext, total8);

            qrn_g5<0,1><<<gGrid, gblk, 0, stream>>>(
                xb, qcur, xq, wtb, bzb, bhb, aggA, aggB, ab);
            scan_p2_kernel<<<dim3(D), blk, 0, stream>>>(aggA, aggB, hini, nullptr, 0, NCH);
            replay2_b<<<rGrid, blk, 0, stream>>>(ab, hini, xb, qnext, xq, total8);

            const u16* ts = qcur; qcur = qnext; qnext = (u16*)ts;
        }
    }
}

// Round 6
// 439.393 us; speedup vs baseline: 1.1914x; 1.1914x over previous
//
#include <hip/hip_runtime.h>
#include <hip/hip_bf16.h>
#include <math.h>

#define D    256
#define BT   128     // chunk length == M tile
#define GN   128     // GEMM N tile per block (2 N-slices)
#define NSEG 32      // BT/4 segments per chunk (GEMM epilogue)

typedef unsigned short u16;
typedef unsigned int   u32;
typedef __attribute__((ext_vector_type(8))) short short8;   // 8 bf16 = 4 VGPRs
typedef __attribute__((ext_vector_type(4))) float floatx4;  // MFMA C/D frag

__device__ __forceinline__ float b2f(u16 v) {
    union { unsigned u; float f; } x; x.u = ((unsigned)v) << 16; return x.f;
}
__device__ __forceinline__ u16 f2b(float f) {
    union { unsigned u; float f; } x; x.f = f;
    unsigned lsb = (x.u >> 16) & 1;
    x.u += 0x7fffu + lsb;                 // RNE
    return (u16)(x.u >> 16);
}
__device__ __forceinline__ float sigm(float x) {
    return __builtin_amdgcn_rcpf(1.0f + __expf(-x));
}
__device__ __forceinline__ float tanhfast(float x) {
    return 1.0f - 2.0f * __builtin_amdgcn_rcpf(__expf(2.0f * x) + 1.0f);
}
__device__ __forceinline__ void async16(const u16* g, u16* l) {
    __builtin_amdgcn_global_load_lds(
        (const __attribute__((address_space(1))) unsigned int*)g,
        (__attribute__((address_space(3))) unsigned int*)l, 16, 0, 0);
}

// ---------------------------------------------------------------------------
// weight transpose + bf16 cast: wt[combo][m][n][k] = bf16(W[k][n])
// layer-0 fold: for l==0, m==0 slab stores q[k]*Wz[k][n]  (z-gate q-fold)
// ---------------------------------------------------------------------------
__global__ __launch_bounds__(256) void wtrans_kernel(
    const float* __restrict__ question,
    const float* __restrict__ Wz_f, const float* __restrict__ Wh_f,
    const float* __restrict__ Wz_b, const float* __restrict__ Wh_b,
    u16* __restrict__ wt)
{
    int id = blockIdx.x * 256 + threadIdx.x;       // < 5*3*65536
    int combo = id / (3 * 65536);
    int rem   = id % (3 * 65536);
    int m = rem >> 16;
    int e = rem & 65535;
    int k = e >> 8, n = e & 255;
    int l   = combo < 3 ? combo : combo - 3;
    int dir = combo < 3 ? 0 : 1;
    float v;
    if (m == 0) {
        const float* Wz = dir ? Wz_b : Wz_f;
        v = Wz[((size_t)l * D + k) * D + n];
        if (l == 0) v *= question[k];              // fold broadcast q into Wz
    } else {
        const float* Wh = dir ? Wh_b : Wh_f;
        int kk = (m == 2) ? (k + D) : k;
        v = Wh[((size_t)l * 2 * D + kk) * D + n];
    }
    wt[(size_t)combo * 3 * 65536 + (size_t)m * 65536 + (size_t)n * D + k] = f2b(v);
}

// ---------------------------------------------------------------------------
// layer-0 h-bias fold: bh0'[n] = bh[0][n] + sum_k q[k] * Wh[0][D+k][n]  (f32)
// blockIdx 0 = fwd, 1 = bwd. Coalesced row reads.
// ---------------------------------------------------------------------------
__global__ __launch_bounds__(256) void bias0_kernel(
    const float* __restrict__ question,
    const float* __restrict__ Wh_f, const float* __restrict__ Wh_b,
    const float* __restrict__ bh_f, const float* __restrict__ bh_b,
    float* __restrict__ bh0f, float* __restrict__ bh0b)
{
    const float* Wh = blockIdx.x ? Wh_b : Wh_f;
    const float* bh = blockIdx.x ? bh_b : bh_f;
    float* out = blockIdx.x ? bh0b : bh0f;
    int n = threadIdx.x;
    float acc = bh[n];                              // layer 0 bias
    for (int k = 0; k < D; ++k)
        acc = fmaf(question[k], Wh[(size_t)(D + k) * D + n], acc);
    out[n] = acc;
}

// ---------------------------------------------------------------------------
// prep: xb = bf16(x) only (layer-0 q/xq are folded; layer>=1 q/xq from replay)
// ---------------------------------------------------------------------------
__global__ __launch_bounds__(256) void prep0_kernel(
    const float* __restrict__ story, u16* __restrict__ xb)
{
    long id = (long)blockIdx.x * 256 + threadIdx.x;
    const float* xp = story + id * 8;
    float4 xa = *(const float4*)xp;
    float4 xc = *(const float4*)(xp + 4);
    float xv[8] = {xa.x, xa.y, xa.z, xa.w, xc.x, xc.y, xc.z, xc.w};
    short8 xs;
    #pragma unroll
    for (int i = 0; i < 8; ++i) xs[i] = (short)f2b(xv[i]);
    *(short8*)(xb + id * 8) = xs;
}

// ---------------------------------------------------------------------------
// LDS stage layouts
// ---------------------------------------------------------------------------
struct StageS {                                               // l>=1: 48KB
    u16 ax [BT * 32]; u16 aq [BT * 32]; u16 axq[BT * 32];    // 8KB each
    u16 bz_[GN * 32]; u16 bx_[GN * 32]; u16 bq_[GN * 32];    // 8KB each
};
struct Stage0 {                                               // l==0: 24KB
    u16 ax [BT * 32]; u16 bz_[GN * 32]; u16 bx_[GN * 32];
};
struct EpiP  { float segA[NSEG][GN]; float segB[NSEG][GN]; }; // 32KB
union __align__(16) SharedP  { StageS st; EpiP ep; };
union __align__(16) SharedP0 { Stage0 st; EpiP ep; };

// ---------------------------------------------------------------------------
// shared epilogue: gates -> (a,b), segment aggregate, in-place exclusive
// prefix, prefix-composed (Aprod,hloc) ab writeout, chunk aggregate.
// ---------------------------------------------------------------------------
__device__ __forceinline__ void gate_epilogue(
    EpiP& ep, int tid, int t0, int n0,
    floatx4 (&accz)[4][2], floatx4 (&acch)[4][2],
    const float* bz, const float* bh,
    float* aggA, float* aggB, u32* abg, int FWD)
{
    const int lane = tid & 63, w = tid >> 6;
    const int wr = w & 1, wc = w >> 1;
    const int lr = lane & 15, quad = lane >> 4;

    float bzn[2], bhn[2];
    #pragma unroll
    for (int ct = 0; ct < 2; ++ct) {
        int n = n0 + wc * 32 + ct * 16 + lr;
        bzn[ct] = bz[n]; bhn[ct] = bh[n];
    }
    float av[4][2][4], bvv[4][2][4];
    #pragma unroll
    for (int rt = 0; rt < 4; ++rt) {
        #pragma unroll
        for (int ct = 0; ct < 2; ++ct) {
            #pragma unroll
            for (int r = 0; r < 4; ++r) {
                float z  = sigm(accz[rt][ct][r] + bzn[ct]);
                float ht = tanhfast(acch[rt][ct][r] + bhn[ct]);
                av[rt][ct][r]  = 1.0f - z;
                bvv[rt][ct][r] = z * ht;
            }
            float A = 1.f, B = 0.f;
            if (FWD) {
                #pragma unroll
                for (int r = 0; r < 4; ++r) { A = av[rt][ct][r] * A; B = fmaf(av[rt][ct][r], B, bvv[rt][ct][r]); }
            } else {
                #pragma unroll
                for (int r = 3; r >= 0; --r) { A = av[rt][ct][r] * A; B = fmaf(av[rt][ct][r], B, bvv[rt][ct][r]); }
            }
            int seg = wr * 16 + rt * 4 + quad;       // = row/4
            int col = wc * 32 + ct * 16 + lr;
            ep.segA[seg][col] = A;
            ep.segB[seg][col] = B;
        }
    }
    __syncthreads();

    if (tid < GN) {
        float A = 1.f, B = 0.f;
        if (FWD) {
            #pragma unroll
            for (int sg = 0; sg < NSEG; ++sg) {
                float a = ep.segA[sg][tid], b = ep.segB[sg][tid];
                ep.segA[sg][tid] = A; ep.segB[sg][tid] = B;
                A = a * A; B = fmaf(a, B, b);
            }
        } else {
            #pragma unroll
            for (int sg = NSEG - 1; sg >= 0; --sg) {
                float a = ep.segA[sg][tid], b = ep.segB[sg][tid];
                ep.segA[sg][tid] = A; ep.segB[sg][tid] = B;
                A = a * A; B = fmaf(a, B, b);
            }
        }
        int c = t0 / BT;
        aggA[(size_t)c * D + n0 + tid] = A;
        aggB[(size_t)c * D + n0 + tid] = B;
    }

    if (abg) {
        __syncthreads();
        #pragma unroll
        for (int rt = 0; rt < 4; ++rt) {
            #pragma unroll
            for (int ct = 0; ct < 2; ++ct) {
                int seg = wr * 16 + rt * 4 + quad;
                int col = wc * 32 + ct * 16 + lr;
                float Pa = ep.segA[seg][col];
                float Pb = ep.segB[seg][col];
                size_t base = (size_t)(t0 + wr * 64 + rt * 16 + quad * 4) * D + n0 + col;
                if (FWD) {
                    #pragma unroll
                    for (int r = 0; r < 4; ++r) {
                        Pa = av[rt][ct][r] * Pa;
                        Pb = fmaf(av[rt][ct][r], Pb, bvv[rt][ct][r]);
                        abg[base + (size_t)r * D] = (u32)f2b(Pa) | ((u32)f2b(Pb) << 16);
                    }
                } else {
                    #pragma unroll
                    for (int r = 3; r >= 0; --r) {
                        Pa = av[rt][ct][r] * Pa;
                        Pb = fmaf(av[rt][ct][r], Pb, bvv[rt][ct][r]);
                        abg[base + (size_t)r * D] = (u32)f2b(Pa) | ((u32)f2b(Pb) << 16);
                    }
                }
            }
        }
    }
}

// ---------------------------------------------------------------------------
// GEMM body, layers 1..2 (R3-proven): 512 thr / 8 waves, 128x128 tile,
// 6-array single-buffered stage, 2 barriers per K-step.
// ---------------------------------------------------------------------------
__device__ __forceinline__ void gemm_body(
    SharedP& sh, int tid, int c, int n0,
    const u16* xbg, const u16* qg, const u16* xqg, const u16* wt,
    const float* bz, const float* bh,
    float* aggA, float* aggB, u32* abg, int FWD)
{
    const int t0   = c * BT;
    const int lane = tid & 63, w = tid >> 6;
    const int wr = w & 1, wc = w >> 1;
    const int lr   = lane & 15, quad = lane >> 4;

    const int swA   = (quad ^ ((lr >> 1) & 3)) * 8;
    const int offA0 = (wr * 64 + lr) * 32 + swA;
    const int offB0 = (wc * 32 + lr) * 32 + swA;

    floatx4 accz[4][2], acch[4][2];
    #pragma unroll
    for (int rt = 0; rt < 4; ++rt)
        #pragma unroll
        for (int ct = 0; ct < 2; ++ct) {
            accz[rt][ct] = (floatx4){0.f,0.f,0.f,0.f};
            acch[rt][ct] = (floatx4){0.f,0.f,0.f,0.f};
        }

    const int lb = (tid & ~63) * 8;

    const int arow = tid >> 2;
    const int agg_ = (tid & 3) ^ ((arow >> 1) & 3);
    const size_t goA = (size_t)(t0 + arow) * D + agg_ * 8;
    const size_t goB = (size_t)(n0 + arow) * D + agg_ * 8;
    const u16* pax  = xbg + goA;
    const u16* paq  = qg  + goA;
    const u16* paxq = xqg + goA;
    const u16* pbz  = wt + goB;
    const u16* pbx  = wt + 65536  + goB;
    const u16* pbq  = wt + 131072 + goB;

    #pragma unroll
    for (int k0 = 0; k0 < D; k0 += 32) {
        async16(pax  + k0, sh.st.ax  + lb);
        async16(paq  + k0, sh.st.aq  + lb);
        async16(paxq + k0, sh.st.axq + lb);
        async16(pbz  + k0, sh.st.bz_ + lb);
        async16(pbx  + k0, sh.st.bx_ + lb);
        async16(pbq  + k0, sh.st.bq_ + lb);
        __syncthreads();

        short8 vz[2], vx[2], vq[2];
        #pragma unroll
        for (int ct = 0; ct < 2; ++ct) {
            vz[ct] = *(const short8*)(sh.st.bz_ + offB0 + ct * 512);
            vx[ct] = *(const short8*)(sh.st.bx_ + offB0 + ct * 512);
            vq[ct] = *(const short8*)(sh.st.bq_ + offB0 + ct * 512);
        }
        #pragma unroll
        for (int rt = 0; rt < 4; ++rt) {
            short8 fxq = *(const short8*)(sh.st.axq + offA0 + rt * 512);
            short8 fx  = *(const short8*)(sh.st.ax  + offA0 + rt * 512);
            short8 fq  = *(const short8*)(sh.st.aq  + offA0 + rt * 512);
            #pragma unroll
            for (int ct = 0; ct < 2; ++ct) {
                accz[rt][ct] = __builtin_amdgcn_mfma_f32_16x16x32_bf16(fxq, vz[ct], accz[rt][ct], 0, 0, 0);
                acch[rt][ct] = __builtin_amdgcn_mfma_f32_16x16x32_bf16(fx , vx[ct], acch[rt][ct], 0, 0, 0);
                acch[rt][ct] = __builtin_amdgcn_mfma_f32_16x16x32_bf16(fq , vq[ct], acch[rt][ct], 0, 0, 0);
            }
        }
        __syncthreads();
    }

    gate_epilogue(sh.ep, tid, t0, n0, accz, acch, bz, bh, aggA, aggB, abg, FWD);
}

// ---------------------------------------------------------------------------
// GEMM body, layer 0 (q folded): stages only xb + Wz' + Wx  (24KB/step)
// ---------------------------------------------------------------------------
__device__ __forceinline__ void gemm0_body(
    SharedP0& sh, int tid, int c, int n0,
    const u16* xbg, const u16* wt,
    const float* bz, const float* bh0,          // bh0 = folded h-bias (256 f32)
    float* aggA, float* aggB, u32* abg, int FWD)
{
    const int t0   = c * BT;
    const int lane = tid & 63, w = tid >> 6;
    const int wr = w & 1, wc = w >> 1;
    const int lr   = lane & 15, quad = lane >> 4;

    const int swA   = (quad ^ ((lr >> 1) & 3)) * 8;
    const int offA0 = (wr * 64 + lr) * 32 + swA;
    const int offB0 = (wc * 32 + lr) * 32 + swA;

    floatx4 accz[4][2], acch[4][2];
    #pragma unroll
    for (int rt = 0; rt < 4; ++rt)
        #pragma unroll
        for (int ct = 0; ct < 2; ++ct) {
            accz[rt][ct] = (floatx4){0.f,0.f,0.f,0.f};
            acch[rt][ct] = (floatx4){0.f,0.f,0.f,0.f};
        }

    const int lb = (tid & ~63) * 8;
    const int arow = tid >> 2;
    const int agg_ = (tid & 3) ^ ((arow >> 1) & 3);
    const size_t goA = (size_t)(t0 + arow) * D + agg_ * 8;
    const size_t goB = (size_t)(n0 + arow) * D + agg_ * 8;
    const u16* pax = xbg + goA;
    const u16* pbz = wt + goB;                   // m=0 slab = diag(q)*Wz
    const u16* pbx = wt + 65536 + goB;           // m=1 slab = Wh x-part

    #pragma unroll
    for (int k0 = 0; k0 < D; k0 += 32) {
        async16(pax + k0, sh.st.ax  + lb);
        async16(pbz + k0, sh.st.bz_ + lb);
        async16(pbx + k0, sh.st.bx_ + lb);
        __syncthreads();

        short8 vz[2], vx[2];
        #pragma unroll
        for (int ct = 0; ct < 2; ++ct) {
            vz[ct] = *(const short8*)(sh.st.bz_ + offB0 + ct * 512);
            vx[ct] = *(const short8*)(sh.st.bx_ + offB0 + ct * 512);
        }
        #pragma unroll
        for (int rt = 0; rt < 4; ++rt) {
            short8 fx = *(const short8*)(sh.st.ax + offA0 + rt * 512);
            #pragma unroll
            for (int ct = 0; ct < 2; ++ct) {
                accz[rt][ct] = __builtin_amdgcn_mfma_f32_16x16x32_bf16(fx, vz[ct], accz[rt][ct], 0, 0, 0);
                acch[rt][ct] = __builtin_amdgcn_mfma_f32_16x16x32_bf16(fx, vx[ct], acch[rt][ct], 0, 0, 0);
            }
        }
        __syncthreads();
    }

    gate_epilogue(sh.ep, tid, t0, n0, accz, acch, bz, bh0, aggA, aggB, abg, FWD);
}

// ---------------------------------------------------------------------------
// kernels
// ---------------------------------------------------------------------------
// layers>=1 single-direction (plan P / l2). grid = NCH*2 = 1024.
template<int FWD, int ABOUT>
__global__ __launch_bounds__(512, 4) void qrn_g5(
    const u16* __restrict__ xbg, const u16* __restrict__ qg,
    const u16* __restrict__ xqg, const u16* __restrict__ wt,
    const float* __restrict__ bz, const float* __restrict__ bh,
    float* __restrict__ aggA, float* __restrict__ aggB,
    u32* __restrict__ abg)
{
    __shared__ SharedP sh;
    const int tid  = threadIdx.x;
    const int bid  = (int)blockIdx.x;
    const int gidx = (bid & 7) * 128 + (bid >> 3);   // XCD-contiguous, bijective
    gemm_body(sh, tid, gidx >> 1, (gidx & 1) * GN,
              xbg, qg, xqg, wt, bz, bh, aggA, aggB, ABOUT ? abg : nullptr, FWD);
}

// layers>=1 combined fwd+bwd: blocks [0,1024) = fwd, [1024,2048) = bwd.
__global__ __launch_bounds__(512, 4) void qrn_gboth(
    const u16* __restrict__ xbg, const u16* __restrict__ qg,
    const u16* __restrict__ xqg,
    const u16* __restrict__ wtF, const u16* __restrict__ wtB,
    const float* __restrict__ bzf, const float* __restrict__ bhf,
    const float* __restrict__ bzb, const float* __restrict__ bhb,
    float* __restrict__ aggAf, float* __restrict__ aggBf,
    float* __restrict__ aggAb, float* __restrict__ aggBb,
    u32* __restrict__ abf, u32* __restrict__ abb)
{
    __shared__ SharedP sh;
    const int tid  = threadIdx.x;
    const int half = (int)blockIdx.x >> 10;       // 0=fwd, 1=bwd
    const int bid  = (int)blockIdx.x & 1023;
    const int gidx = (bid & 7) * 128 + (bid >> 3);
    gemm_body(sh, tid, gidx >> 1, (gidx & 1) * GN,
              xbg, qg, xqg,
              half ? wtB : wtF,
              half ? bzb : bzf, half ? bhb : bhf,
              half ? aggAb : aggAf, half ? aggBb : aggBf,
              half ? abb : abf, half ? 0 : 1);
}

// layer-0 single-direction (plan P). grid = NCH*2 = 1024.
template<int FWD>
__global__ __launch_bounds__(512, 4) void qrn_g0(
    const u16* __restrict__ xbg, const u16* __restrict__ wt,
    const float* __restrict__ bz, const float* __restrict__ bh0,
    float* __restrict__ aggA, float* __restrict__ aggB,
    u32* __restrict__ abg)
{
    __shared__ SharedP0 sh;
    const int tid  = threadIdx.x;
    const int bid  = (int)blockIdx.x;
    const int gidx = (bid & 7) * 128 + (bid >> 3);
    gemm0_body(sh, tid, gidx >> 1, (gidx & 1) * GN,
               xbg, wt, bz, bh0, aggA, aggB, abg, FWD);
}

// layer-0 combined fwd+bwd: blocks [0,1024) = fwd, [1024,2048) = bwd.
__global__ __launch_bounds__(512, 4) void qrn_g0both(
    const u16* __restrict__ xbg,
    const u16* __restrict__ wtF, const u16* __restrict__ wtB,
    const float* __restrict__ bzf, const float* __restrict__ bh0f,
    const float* __restrict__ bzb, const float* __restrict__ bh0b,
    float* __restrict__ aggAf, float* __restrict__ aggBf,
    float* __restrict__ aggAb, float* __restrict__ aggBb,
    u32* __restrict__ abf, u32* __restrict__ abb)
{
    __shared__ SharedP0 sh;
    const int tid  = threadIdx.x;
    const int half = (int)blockIdx.x >> 10;
    const int bid  = (int)blockIdx.x & 1023;
    const int gidx = (bid & 7) * 128 + (bid >> 3);
    gemm0_body(sh, tid, gidx >> 1, (gidx & 1) * GN,
               xbg,
               half ? wtB : wtF,
               half ? bzb : bzf, half ? bh0b : bh0f,
               half ? aggAb : aggAf, half ? aggBb : aggBf,
               half ? abb : abf, half ? 0 : 1);
}

// ===========================================================================
// elementwise replay: ab holds (Aprod_t, hloc_t) packed bf16.
// h_t = Aprod_t * hinit[chunk] + hloc_t. Pure streaming, vec8.
// ===========================================================================
__global__ __launch_bounds__(256) void replay2_fb(
    const u32* __restrict__ abf, const u32* __restrict__ abb,
    const float* __restrict__ hinif, const float* __restrict__ hinib,
    const u16* __restrict__ xb, u16* __restrict__ qout, u16* __restrict__ xq,
    int total8)
{
    for (int id = (int)blockIdx.x * 256 + (int)threadIdx.x; id < total8;
         id += (int)gridDim.x * 256) {
        int t  = id >> 5;
        int n0 = (id & 31) * 8;
        int c  = t >> 7;
        size_t o  = (size_t)t * D + n0;
        size_t hc = (size_t)c * D + n0;
        uint4 f0 = *(const uint4*)(abf + o);
        uint4 f1 = *(const uint4*)(abf + o + 4);
        uint4 g0 = *(const uint4*)(abb + o);
        uint4 g1 = *(const uint4*)(abb + o + 4);
        float4 hf0 = *(const float4*)(hinif + hc);
        float4 hf1 = *(const float4*)(hinif + hc + 4);
        float4 hb0 = *(const float4*)(hinib + hc);
        float4 hb1 = *(const float4*)(hinib + hc + 4);
        short8 xv = *(const short8*)(xb + o);
        u32 fa[8] = {f0.x, f0.y, f0.z, f0.w, f1.x, f1.y, f1.z, f1.w};
        u32 ga[8] = {g0.x, g0.y, g0.z, g0.w, g1.x, g1.y, g1.z, g1.w};
        float hfv[8] = {hf0.x, hf0.y, hf0.z, hf0.w, hf1.x, hf1.y, hf1.z, hf1.w};
        float hbv[8] = {hb0.x, hb0.y, hb0.z, hb0.w, hb1.x, hb1.y, hb1.z, hb1.w};
        short8 qs, xqs;
        #pragma unroll
        for (int i = 0; i < 8; ++i) {
            float hF = fmaf(b2f((u16)(fa[i] & 0xffff)), hfv[i], b2f((u16)(fa[i] >> 16)));
            float hB = fmaf(b2f((u16)(ga[i] & 0xffff)), hbv[i], b2f((u16)(ga[i] >> 16)));
            u16 qb = f2b(hF + hB);
            qs[i]  = (short)qb;
            xqs[i] = (short)f2b(b2f((u16)xv[i]) * b2f(qb));
        }
        *(short8*)(qout + o) = qs;
        *(short8*)(xq + o)   = xqs;
    }
}

// plan-P fallback replays (elementwise, same prefix semantics)
__global__ __launch_bounds__(256) void replay2_f(
    const u32* __restrict__ abg, const float* __restrict__ hini,
    u16* __restrict__ qout, int total8)
{
    for (int id = (int)blockIdx.x * 256 + (int)threadIdx.x; id < total8;
         id += (int)gridDim.x * 256) {
        int t  = id >> 5;
        int n0 = (id & 31) * 8;
        int c  = t >> 7;
        size_t o  = (size_t)t * D + n0;
        size_t hc = (size_t)c * D + n0;
        uint4 f0 = *(const uint4*)(abg + o);
        uint4 f1 = *(const uint4*)(abg + o + 4);
        float4 hf0 = *(const float4*)(hini + hc);
        float4 hf1 = *(const float4*)(hini + hc + 4);
        u32 fa[8] = {f0.x, f0.y, f0.z, f0.w, f1.x, f1.y, f1.z, f1.w};
        float hfv[8] = {hf0.x, hf0.y, hf0.z, hf0.w, hf1.x, hf1.y, hf1.z, hf1.w};
        short8 qs;
        #pragma unroll
        for (int i = 0; i < 8; ++i) {
            float hF = fmaf(b2f((u16)(fa[i] & 0xffff)), hfv[i], b2f((u16)(fa[i] >> 16)));
            qs[i] = (short)f2b(hF);
        }
        *(short8*)(qout + o) = qs;
    }
}

__global__ __launch_bounds__(256) void replay2_b(
    const u32* __restrict__ abg, const float* __restrict__ hini,
    const u16* __restrict__ xb, u16* __restrict__ qout, u16* __restrict__ xq,
    int total8)
{
    for (int id = (int)blockIdx.x * 256 + (int)threadIdx.x; id < total8;
         id += (int)gridDim.x * 256) {
        int t  = id >> 5;
        int n0 = (id & 31) * 8;
        int c  = t >> 7;
        size_t o  = (size_t)t * D + n0;
        size_t hc = (size_t)c * D + n0;
        uint4 g0 = *(const uint4*)(abg + o);
        uint4 g1 = *(const uint4*)(abg + o + 4);
        float4 hb0 = *(const float4*)(hini + hc);
        float4 hb1 = *(const float4*)(hini + hc + 4);
        short8 qold = *(const short8*)(qout + o);
        short8 xv   = *(const short8*)(xb + o);
        u32 ga[8] = {g0.x, g0.y, g0.z, g0.w, g1.x, g1.y, g1.z, g1.w};
        float hbv[8] = {hb0.x, hb0.y, hb0.z, hb0.w, hb1.x, hb1.y, hb1.z, hb1.w};
        short8 qs, xqs;
        #pragma unroll
        for (int i = 0; i < 8; ++i) {
            float hB = fmaf(b2f((u16)(ga[i] & 0xffff)), hbv[i], b2f((u16)(ga[i] >> 16)));
            float qn = b2f((u16)qold[i]) + hB;
            u16 qb = f2b(qn);
            qs[i]  = (short)qb;
            xqs[i] = (short)f2b(b2f((u16)xv[i]) * b2f(qb));
        }
        *(short8*)(qout + o) = qs;
        *(short8*)(xq + o)   = xqs;
    }
}

// ---------------------------------------------------------------------------
// inter-chunk scans
// ---------------------------------------------------------------------------
__device__ __forceinline__ void scan_body(
    const float* aggA, const float* aggB, float* hinit, float* out_final,
    int fwd, int nch, int n, int tid)
{
    __shared__ float sA[256], sB[256];
    const int per = nch >> 8;
    float lA[4], lB[4];
    float A = 1.f, B = 0.f;
    for (int j = 0; j < per; ++j) {
        int pidx = tid * per + j;
        int c = fwd ? pidx : (nch - 1 - pidx);
        float a = aggA[(size_t)c * D + n];
        float b = aggB[(size_t)c * D + n];
        lA[j] = a; lB[j] = b;
        A = a * A;
        B = fmaf(a, B, b);
    }
    sA[tid] = A; sB[tid] = B;
    __syncthreads();
    for (int off = 1; off < 256; off <<= 1) {
        float pA = 1.f, pB = 0.f;
        if (tid >= off) { pA = sA[tid - off]; pB = sB[tid - off]; }
        __syncthreads();
        if (tid >= off) {
            float cA = sA[tid], cB = sB[tid];
            sA[tid] = pA * cA;
            sB[tid] = fmaf(cA, pB, cB);
        }
        __syncthreads();
    }
    float eB = (tid > 0) ? sB[tid - 1] : 0.f;
    for (int j = 0; j < per; ++j) {
        int pidx = tid * per + j;
        int c = fwd ? pidx : (nch - 1 - pidx);
        hinit[(size_t)c * D + n] = eB;
        eB = fmaf(lA[j], eB, lB[j]);
    }
    if (out_final != nullptr && tid == 0) out_final[n] = sB[255];
}

__global__ __launch_bounds__(256) void scan_p2_kernel(
    const float* __restrict__ aggA, const float* __restrict__ aggB,
    float* __restrict__ hinit, float* __restrict__ out_final, int fwd, int nch)
{
    scan_body(aggA, aggB, hinit, out_final, fwd, nch, blockIdx.x, threadIdx.x);
}

__global__ __launch_bounds__(256) void scan_dual_kernel(
    const float* __restrict__ aggAf, const float* __restrict__ aggBf, float* __restrict__ hf,
    const float* __restrict__ aggAb, const float* __restrict__ aggBb, float* __restrict__ hb,
    int nch)
{
    int b = blockIdx.x;
    int fwd = (b < D) ? 1 : 0;
    int n = fwd ? b : (b - D);
    scan_body(fwd ? aggAf : aggAb, fwd ? aggBf : aggBb,
              fwd ? hf : hb, nullptr, fwd, nch, n, threadIdx.x);
}

// ---------------------------------------------------------------------------
extern "C" void kernel_launch(void* const* d_in, const int* in_sizes, int n_in,
                              void* d_out, int out_size, void* d_ws, size_t ws_size,
                              hipStream_t stream) {
    const float* story    = (const float*)d_in[0];
    const float* question = (const float*)d_in[1];
    const float* Wz_f = (const float*)d_in[2];
    const float* bz_f = (const float*)d_in[3];
    const float* Wh_f = (const float*)d_in[4];
    const float* bh_f = (const float*)d_in[5];
    const float* Wz_b = (const float*)d_in[6];
    const float* bz_b = (const float*)d_in[7];
    const float* Wh_b = (const float*)d_in[8];
    const float* bh_b = (const float*)d_in[9];

    const int T    = in_sizes[0] / D;            // 65536
    const int NCH  = T / BT;                     // 512
    const size_t TD = (size_t)T * D;
    const size_t WTE = 5 * 3 * 65536;
    const int total8 = T * 32;                   // TD/8

    // plan F: xb,q,xq (bf16) + wt + abf,abb (u32) + 4 agg + 2 bias  (~231 MB)
    const size_t needF = 3 * TD * 2 + WTE * 2 + 2 * TD * 4
                       + (size_t)4 * NCH * D * 4 + 2 * D * 4 + 4096;
    const bool planF = ws_size >= needF;

    dim3 blk(256);
    dim3 gblk(512);                              // 8 waves, 64x32 wave tile
    dim3 gGrid((unsigned)(NCH * 2));             // 1024 (one dir, GN=128)
    dim3 g2Grid((unsigned)(NCH * 4));            // 2048 (both dirs)
    dim3 rGrid(2048);                            // replay grid-stride
    dim3 pGrid((unsigned)(TD / 8 / 256));

    if (planF) {
        u16* xb = (u16*)d_ws;
        u16* q  = xb + TD;
        u16* xq = q  + TD;
        u16* wt = xq + TD;
        u32* abf = (u32*)(wt + WTE);
        u32* abb = abf + TD;
        float* aggAf = (float*)(abb + TD);
        float* aggBf = aggAf + (size_t)NCH * D;
        float* aggAb = aggBf + (size_t)NCH * D;
        float* aggBb = aggAb + (size_t)NCH * D;
        float* bh0f  = aggBb + (size_t)NCH * D;
        float* bh0b  = bh0f + D;
        float* hinif = aggBf;                    // alias (safe)
        float* hinib = aggBb;                    // alias (safe)

        wtrans_kernel<<<dim3(5 * 3 * 65536 / 256), blk, 0, stream>>>(
            question, Wz_f, Wh_f, Wz_b, Wh_b, wt);
        bias0_kernel<<<dim3(2), blk, 0, stream>>>(
            question, Wh_f, Wh_b, bh_f, bh_b, bh0f, bh0b);
        prep0_kernel<<<pGrid, blk, 0, stream>>>(story, xb);

        for (int l = 0; l < 3; ++l) {
            const u16*   wtf = wt + (size_t)l * 3 * 65536;
            const float* bzf = bz_f + (size_t)l * D;
            const float* bhf = bh_f + (size_t)l * D;

            if (l == 2) {
                qrn_g5<1,0><<<gGrid, gblk, 0, stream>>>(
                    xb, q, xq, wtf, bzf, bhf, aggAf, aggBf, nullptr);
                scan_p2_kernel<<<dim3(D), blk, 0, stream>>>(
                    aggAf, aggBf, hinif, (float*)d_out, 1, NCH);
                break;
            }
            const u16*   wtb = wt + (size_t)(3 + l) * 3 * 65536;
            const float* bzb = bz_b + (size_t)l * D;
            const float* bhb = bh_b + (size_t)l * D;

            if (l == 0) {
                qrn_g0both<<<g2Grid, gblk, 0, stream>>>(
                    xb, wtf, wtb, bzf, bh0f, bzb, bh0b,
                    aggAf, aggBf, aggAb, aggBb, abf, abb);
            } else {
                qrn_gboth<<<g2Grid, gblk, 0, stream>>>(
                    xb, q, xq, wtf, wtb, bzf, bhf, bzb, bhb,
                    aggAf, aggBf, aggAb, aggBb, abf, abb);
            }
            scan_dual_kernel<<<dim3(2 * D), blk, 0, stream>>>(
                aggAf, aggBf, hinif, aggAb, aggBb, hinib, NCH);
            replay2_fb<<<rGrid, blk, 0, stream>>>(
                abf, abb, hinif, hinib, xb, q, xq, total8);
        }
    } else {
        // ---------------- plan P fallback ----------------
        u16* xb = (u16*)d_ws;
        u16* qA = xb + TD;
        u16* qB = qA + TD;
        u16* xq = qB + TD;
        u16* wt = xq + TD;
        u32*   ab   = (u32*)(wt + WTE);
        float* aggA = (float*)(ab + TD);
        float* aggB = aggA + (size_t)NCH * D;
        float* bh0f = aggB + (size_t)NCH * D;
        float* bh0b = bh0f + D;
        float* hini = aggB;

        wtrans_kernel<<<dim3(5 * 3 * 65536 / 256), blk, 0, stream>>>(
            question, Wz_f, Wh_f, Wz_b, Wh_b, wt);
        bias0_kernel<<<dim3(2), blk, 0, stream>>>(
            question, Wh_f, Wh_b, bh_f, bh_b, bh0f, bh0b);
        prep0_kernel<<<pGrid, blk, 0, stream>>>(story, xb);

        const u16* qcur  = qA;
        u16*       qnext = qB;

        for (int l = 0; l < 3; ++l) {
            const u16*   wtf = wt + (size_t)l * 3 * 65536;
            const float* bzf = bz_f + (size_t)l * D;
            const float* bhf = bh_f + (size_t)l * D;

            if (l == 2) {
                qrn_g5<1,0><<<gGrid, gblk, 0, stream>>>(
                    xb, qcur, xq, wtf, bzf, bhf, aggA, aggB, nullptr);
                scan_p2_kernel<<<dim3(D), blk, 0, stream>>>(
                    aggA, aggB, hini, (float*)d_out, 1, NCH);
                break;
            }
            const u16*   wtb = wt + (size_t)(3 + l) * 3 * 65536;
            const float* bzb = bz_b + (size_t)l * D;
            const float* bhb = bh_b + (size_t)l * D;

            if (l == 0) {
                qrn_g0<1><<<gGrid, gblk, 0, stream>>>(
                    xb, wtf, bzf, bh0f, aggA, aggB, ab);
                scan_p2_kernel<<<dim3(D), blk, 0, stream>>>(aggA, aggB, hini, nullptr, 1, NCH);
                replay2_f<<<rGrid, blk, 0, stream>>>(ab, hini, qnext, total8);

                qrn_g0<0><<<gGrid, gblk, 0, stream>>>(
                    xb, wtb, bzb, bh0b, aggA, aggB, ab);
                scan_p2_kernel<<<dim3(D), blk, 0, stream>>>(aggA, aggB, hini, nullptr, 0, NCH);
                replay2_b<<<rGrid, blk, 0, stream>>>(ab, hini, xb, qnext, xq, total8);
            } else {
                qrn_g5<1,1><<<gGrid, gblk, 0, stream>>>(
                    xb, qcur, xq, wtf, bzf, bhf, aggA, aggB, ab);
                scan_p2_kernel<<<dim3(D), blk, 0, stream>>>(aggA, aggB, hini, nullptr, 1, NCH);
                replay2_f<<<rGrid, blk, 0, stream>>>(ab, hini, qnext, total8);

                qrn_g5<0,1><<<gGrid, gblk, 0, stream>>>(
                    xb, qcur, xq, wtb, bzb, bhb, aggA, aggB, ab);
                scan_p2_kernel<<<dim3(D), blk, 0, stream>>>(aggA, aggB, hini, nullptr, 0, NCH);
                replay2_b<<<rGrid, blk, 0, stream>>>(ab, hini, xb, qnext, xq, total8);
            }
            const u16* ts = qcur; qcur = qnext; qnext = (u16*)ts;
        }
    }
}

// Round 7
// 413.917 us; speedup vs baseline: 1.2647x; 1.0615x over previous
//
#include <hip/hip_runtime.h>
#include <hip/hip_bf16.h>
#include <math.h>

#define D    256
#define BT   128     // chunk length == M tile
#define GN   128     // GEMM N tile per block (2 N-slices)
#define NSEG 32      // BT/4 segments per chunk (GEMM epilogue)

typedef unsigned short u16;
typedef unsigned int   u32;
typedef __attribute__((ext_vector_type(8))) short short8;   // 8 bf16 = 4 VGPRs
typedef __attribute__((ext_vector_type(4))) float floatx4;  // MFMA C/D frag

__device__ __forceinline__ float b2f(u16 v) {
    union { unsigned u; float f; } x; x.u = ((unsigned)v) << 16; return x.f;
}
__device__ __forceinline__ u16 f2b(float f) {
    union { unsigned u; float f; } x; x.f = f;
    unsigned lsb = (x.u >> 16) & 1;
    x.u += 0x7fffu + lsb;                 // RNE
    return (u16)(x.u >> 16);
}
__device__ __forceinline__ float sigm(float x) {
    return __builtin_amdgcn_rcpf(1.0f + __expf(-x));
}
__device__ __forceinline__ float tanhfast(float x) {
    return 1.0f - 2.0f * __builtin_amdgcn_rcpf(__expf(2.0f * x) + 1.0f);
}
__device__ __forceinline__ void async16(const u16* g, u16* l) {
    __builtin_amdgcn_global_load_lds(
        (const __attribute__((address_space(1))) unsigned int*)g,
        (__attribute__((address_space(3))) unsigned int*)l, 16, 0, 0);
}

// ---------------------------------------------------------------------------
// weight transpose + bf16 cast: wt[combo][m][n][k] = bf16(W[k][n])
// layer-0 fold: for l==0, m==0 slab stores q[k]*Wz[k][n]  (z-gate q-fold)
// ---------------------------------------------------------------------------
__global__ __launch_bounds__(256) void wtrans_kernel(
    const float* __restrict__ question,
    const float* __restrict__ Wz_f, const float* __restrict__ Wh_f,
    const float* __restrict__ Wz_b, const float* __restrict__ Wh_b,
    u16* __restrict__ wt)
{
    int id = blockIdx.x * 256 + threadIdx.x;       // < 5*3*65536
    int combo = id / (3 * 65536);
    int rem   = id % (3 * 65536);
    int m = rem >> 16;
    int e = rem & 65535;
    int k = e >> 8, n = e & 255;
    int l   = combo < 3 ? combo : combo - 3;
    int dir = combo < 3 ? 0 : 1;
    float v;
    if (m == 0) {
        const float* Wz = dir ? Wz_b : Wz_f;
        v = Wz[((size_t)l * D + k) * D + n];
        if (l == 0) v *= question[k];              // fold broadcast q into Wz
    } else {
        const float* Wh = dir ? Wh_b : Wh_f;
        int kk = (m == 2) ? (k + D) : k;
        v = Wh[((size_t)l * 2 * D + kk) * D + n];
    }
    wt[(size_t)combo * 3 * 65536 + (size_t)m * 65536 + (size_t)n * D + k] = f2b(v);
}

// ---------------------------------------------------------------------------
// layer-0 h-bias fold: bh0'[n] = bh[0][n] + sum_k q[k] * Wh[0][D+k][n]  (f32)
// ---------------------------------------------------------------------------
__global__ __launch_bounds__(256) void bias0_kernel(
    const float* __restrict__ question,
    const float* __restrict__ Wh_f, const float* __restrict__ Wh_b,
    const float* __restrict__ bh_f, const float* __restrict__ bh_b,
    float* __restrict__ bh0f, float* __restrict__ bh0b)
{
    const float* Wh = blockIdx.x ? Wh_b : Wh_f;
    const float* bh = blockIdx.x ? bh_b : bh_f;
    float* out = blockIdx.x ? bh0b : bh0f;
    int n = threadIdx.x;
    float acc = bh[n];                              // layer 0 bias
    for (int k = 0; k < D; ++k)
        acc = fmaf(question[k], Wh[(size_t)(D + k) * D + n], acc);
    out[n] = acc;
}

// ---------------------------------------------------------------------------
// prep: xb = bf16(x) only
// ---------------------------------------------------------------------------
__global__ __launch_bounds__(256) void prep0_kernel(
    const float* __restrict__ story, u16* __restrict__ xb)
{
    long id = (long)blockIdx.x * 256 + threadIdx.x;
    const float* xp = story + id * 8;
    float4 xa = *(const float4*)xp;
    float4 xc = *(const float4*)(xp + 4);
    float xv[8] = {xa.x, xa.y, xa.z, xa.w, xc.x, xc.y, xc.z, xc.w};
    short8 xs;
    #pragma unroll
    for (int i = 0; i < 8; ++i) xs[i] = (short)f2b(xv[i]);
    *(short8*)(xb + id * 8) = xs;
}

// ---------------------------------------------------------------------------
// LDS stage layouts: A double-buffered (prefetch target), B single-buffered
// ---------------------------------------------------------------------------
struct StageS {                                               // l>=1: 72KB
    u16 ax [2][BT * 32]; u16 aq [2][BT * 32]; u16 axq[2][BT * 32]; // 48KB
    u16 bz_[GN * 32]; u16 bx_[GN * 32]; u16 bq_[GN * 32];          // 24KB
};
struct Stage0 {                                               // l==0: 32KB
    u16 ax [2][BT * 32];                                           // 16KB
    u16 bz_[GN * 32]; u16 bx_[GN * 32];                            // 16KB
};
struct EpiP  { float segA[NSEG][GN]; float segB[NSEG][GN]; }; // 32KB
union __align__(16) SharedP  { StageS st; EpiP ep; };
union __align__(16) SharedP0 { Stage0 st; EpiP ep; };

// ---------------------------------------------------------------------------
// shared epilogue: gates -> (a,b), segment aggregate, in-place exclusive
// prefix, prefix-composed (Aprod,hloc) ab writeout, chunk aggregate.
// ---------------------------------------------------------------------------
__device__ __forceinline__ void gate_epilogue(
    EpiP& ep, int tid, int t0, int n0,
    floatx4 (&accz)[4][2], floatx4 (&acch)[4][2],
    const float* bz, const float* bh,
    float* aggA, float* aggB, u32* abg, int FWD)
{
    const int lane = tid & 63, w = tid >> 6;
    const int wr = w & 1, wc = w >> 1;
    const int lr = lane & 15, quad = lane >> 4;

    float bzn[2], bhn[2];
    #pragma unroll
    for (int ct = 0; ct < 2; ++ct) {
        int n = n0 + wc * 32 + ct * 16 + lr;
        bzn[ct] = bz[n]; bhn[ct] = bh[n];
    }
    float av[4][2][4], bvv[4][2][4];
    #pragma unroll
    for (int rt = 0; rt < 4; ++rt) {
        #pragma unroll
        for (int ct = 0; ct < 2; ++ct) {
            #pragma unroll
            for (int r = 0; r < 4; ++r) {
                float z  = sigm(accz[rt][ct][r] + bzn[ct]);
                float ht = tanhfast(acch[rt][ct][r] + bhn[ct]);
                av[rt][ct][r]  = 1.0f - z;
                bvv[rt][ct][r] = z * ht;
            }
            float A = 1.f, B = 0.f;
            if (FWD) {
                #pragma unroll
                for (int r = 0; r < 4; ++r) { A = av[rt][ct][r] * A; B = fmaf(av[rt][ct][r], B, bvv[rt][ct][r]); }
            } else {
                #pragma unroll
                for (int r = 3; r >= 0; --r) { A = av[rt][ct][r] * A; B = fmaf(av[rt][ct][r], B, bvv[rt][ct][r]); }
            }
            int seg = wr * 16 + rt * 4 + quad;       // = row/4
            int col = wc * 32 + ct * 16 + lr;
            ep.segA[seg][col] = A;
            ep.segB[seg][col] = B;
        }
    }
    __syncthreads();

    if (tid < GN) {
        float A = 1.f, B = 0.f;
        if (FWD) {
            #pragma unroll
            for (int sg = 0; sg < NSEG; ++sg) {
                float a = ep.segA[sg][tid], b = ep.segB[sg][tid];
                ep.segA[sg][tid] = A; ep.segB[sg][tid] = B;
                A = a * A; B = fmaf(a, B, b);
            }
        } else {
            #pragma unroll
            for (int sg = NSEG - 1; sg >= 0; --sg) {
                float a = ep.segA[sg][tid], b = ep.segB[sg][tid];
                ep.segA[sg][tid] = A; ep.segB[sg][tid] = B;
                A = a * A; B = fmaf(a, B, b);
            }
        }
        int c = t0 / BT;
        aggA[(size_t)c * D + n0 + tid] = A;
        aggB[(size_t)c * D + n0 + tid] = B;
    }

    if (abg) {
        __syncthreads();
        #pragma unroll
        for (int rt = 0; rt < 4; ++rt) {
            #pragma unroll
            for (int ct = 0; ct < 2; ++ct) {
                int seg = wr * 16 + rt * 4 + quad;
                int col = wc * 32 + ct * 16 + lr;
                float Pa = ep.segA[seg][col];
                float Pb = ep.segB[seg][col];
                size_t base = (size_t)(t0 + wr * 64 + rt * 16 + quad * 4) * D + n0 + col;
                if (FWD) {
                    #pragma unroll
                    for (int r = 0; r < 4; ++r) {
                        Pa = av[rt][ct][r] * Pa;
                        Pb = fmaf(av[rt][ct][r], Pb, bvv[rt][ct][r]);
                        abg[base + (size_t)r * D] = (u32)f2b(Pa) | ((u32)f2b(Pb) << 16);
                    }
                } else {
                    #pragma unroll
                    for (int r = 3; r >= 0; --r) {
                        Pa = av[rt][ct][r] * Pa;
                        Pb = fmaf(av[rt][ct][r], Pb, bvv[rt][ct][r]);
                        abg[base + (size_t)r * D] = (u32)f2b(Pa) | ((u32)f2b(Pb) << 16);
                    }
                }
            }
        }
    }
}

// ---------------------------------------------------------------------------
// GEMM body, layers 1..2: A-dbuf + counted vmcnt pipeline.
// Per K-step: issue B(k) [L2], issue A(k+1) [HBM, prefetch], vmcnt(3)
// (waits A(k)+B(k), leaves A(k+1) in flight), barrier, ds_read+MFMA, barrier.
// ---------------------------------------------------------------------------
__device__ __forceinline__ void gemm_body(
    SharedP& sh, int tid, int c, int n0,
    const u16* xbg, const u16* qg, const u16* xqg, const u16* wt,
    const float* bz, const float* bh,
    float* aggA, float* aggB, u32* abg, int FWD)
{
    const int t0   = c * BT;
    const int lane = tid & 63, w = tid >> 6;
    const int wr = w & 1, wc = w >> 1;
    const int lr   = lane & 15, quad = lane >> 4;

    const int swA   = (quad ^ ((lr >> 1) & 3)) * 8;
    const int offA0 = (wr * 64 + lr) * 32 + swA;
    const int offB0 = (wc * 32 + lr) * 32 + swA;

    floatx4 accz[4][2], acch[4][2];
    #pragma unroll
    for (int rt = 0; rt < 4; ++rt)
        #pragma unroll
        for (int ct = 0; ct < 2; ++ct) {
            accz[rt][ct] = (floatx4){0.f,0.f,0.f,0.f};
            acch[rt][ct] = (floatx4){0.f,0.f,0.f,0.f};
        }

    const int lb = (tid & ~63) * 8;

    const int arow = tid >> 2;
    const int agg_ = (tid & 3) ^ ((arow >> 1) & 3);
    const size_t goA = (size_t)(t0 + arow) * D + agg_ * 8;
    const size_t goB = (size_t)(n0 + arow) * D + agg_ * 8;
    const u16* pax  = xbg + goA;
    const u16* paq  = qg  + goA;
    const u16* paxq = xqg + goA;
    const u16* pbz  = wt + goB;
    const u16* pbx  = wt + 65536  + goB;
    const u16* pbq  = wt + 131072 + goB;

    // prologue: A(0) in flight
    async16(pax , sh.st.ax [0] + lb);
    async16(paq , sh.st.aq [0] + lb);
    async16(paxq, sh.st.axq[0] + lb);

    #pragma unroll
    for (int kk = 0; kk < 8; ++kk) {
        const int cur = kk & 1, nxt = cur ^ 1;
        const int k0 = kk * 32;
        // B for this step (L2-resident weights)
        async16(pbz + k0, sh.st.bz_ + lb);
        async16(pbx + k0, sh.st.bx_ + lb);
        async16(pbq + k0, sh.st.bq_ + lb);
        if (kk < 7) {
            // A prefetch for next step (HBM latency spans this iteration)
            async16(pax  + k0 + 32, sh.st.ax [nxt] + lb);
            async16(paq  + k0 + 32, sh.st.aq [nxt] + lb);
            async16(paxq + k0 + 32, sh.st.axq[nxt] + lb);
            asm volatile("s_waitcnt vmcnt(3)" ::: "memory");  // A(k)+B(k) done
        } else {
            asm volatile("s_waitcnt vmcnt(0)" ::: "memory");
        }
        __builtin_amdgcn_s_barrier();
        asm volatile("" ::: "memory");

        short8 vz[2], vx[2], vq[2];
        #pragma unroll
        for (int ct = 0; ct < 2; ++ct) {
            vz[ct] = *(const short8*)(sh.st.bz_ + offB0 + ct * 512);
            vx[ct] = *(const short8*)(sh.st.bx_ + offB0 + ct * 512);
            vq[ct] = *(const short8*)(sh.st.bq_ + offB0 + ct * 512);
        }
        #pragma unroll
        for (int rt = 0; rt < 4; ++rt) {
            short8 fxq = *(const short8*)(sh.st.axq[cur] + offA0 + rt * 512);
            short8 fx  = *(const short8*)(sh.st.ax [cur] + offA0 + rt * 512);
            short8 fq  = *(const short8*)(sh.st.aq [cur] + offA0 + rt * 512);
            #pragma unroll
            for (int ct = 0; ct < 2; ++ct) {
                accz[rt][ct] = __builtin_amdgcn_mfma_f32_16x16x32_bf16(fxq, vz[ct], accz[rt][ct], 0, 0, 0);
                acch[rt][ct] = __builtin_amdgcn_mfma_f32_16x16x32_bf16(fx , vx[ct], acch[rt][ct], 0, 0, 0);
                acch[rt][ct] = __builtin_amdgcn_mfma_f32_16x16x32_bf16(fq , vq[ct], acch[rt][ct], 0, 0, 0);
            }
        }
        asm volatile("" ::: "memory");
        __builtin_amdgcn_s_barrier();   // reads done -> next iter may overwrite
        asm volatile("" ::: "memory");
    }

    gate_epilogue(sh.ep, tid, t0, n0, accz, acch, bz, bh, aggA, aggB, abg, FWD);
}

// ---------------------------------------------------------------------------
// GEMM body, layer 0 (q folded): A=xb dbuf, B = {Wz', Wx}. vmcnt(1).
// ---------------------------------------------------------------------------
__device__ __forceinline__ void gemm0_body(
    SharedP0& sh, int tid, int c, int n0,
    const u16* xbg, const u16* wt,
    const float* bz, const float* bh0,
    float* aggA, float* aggB, u32* abg, int FWD)
{
    const int t0   = c * BT;
    const int lane = tid & 63, w = tid >> 6;
    const int wr = w & 1, wc = w >> 1;
    const int lr   = lane & 15, quad = lane >> 4;

    const int swA   = (quad ^ ((lr >> 1) & 3)) * 8;
    const int offA0 = (wr * 64 + lr) * 32 + swA;
    const int offB0 = (wc * 32 + lr) * 32 + swA;

    floatx4 accz[4][2], acch[4][2];
    #pragma unroll
    for (int rt = 0; rt < 4; ++rt)
        #pragma unroll
        for (int ct = 0; ct < 2; ++ct) {
            accz[rt][ct] = (floatx4){0.f,0.f,0.f,0.f};
            acch[rt][ct] = (floatx4){0.f,0.f,0.f,0.f};
        }

    const int lb = (tid & ~63) * 8;
    const int arow = tid >> 2;
    const int agg_ = (tid & 3) ^ ((arow >> 1) & 3);
    const size_t goA = (size_t)(t0 + arow) * D + agg_ * 8;
    const size_t goB = (size_t)(n0 + arow) * D + agg_ * 8;
    const u16* pax = xbg + goA;
    const u16* pbz = wt + goB;                   // m=0 slab = diag(q)*Wz
    const u16* pbx = wt + 65536 + goB;           // m=1 slab = Wh x-part

    async16(pax, sh.st.ax[0] + lb);              // prologue A(0)

    #pragma unroll
    for (int kk = 0; kk < 8; ++kk) {
        const int cur = kk & 1, nxt = cur ^ 1;
        const int k0 = kk * 32;
        async16(pbz + k0, sh.st.bz_ + lb);
        async16(pbx + k0, sh.st.bx_ + lb);
        if (kk < 7) {
            async16(pax + k0 + 32, sh.st.ax[nxt] + lb);
            asm volatile("s_waitcnt vmcnt(1)" ::: "memory");
        } else {
            asm volatile("s_waitcnt vmcnt(0)" ::: "memory");
        }
        __builtin_amdgcn_s_barrier();
        asm volatile("" ::: "memory");

        short8 vz[2], vx[2];
        #pragma unroll
        for (int ct = 0; ct < 2; ++ct) {
            vz[ct] = *(const short8*)(sh.st.bz_ + offB0 + ct * 512);
            vx[ct] = *(const short8*)(sh.st.bx_ + offB0 + ct * 512);
        }
        #pragma unroll
        for (int rt = 0; rt < 4; ++rt) {
            short8 fx = *(const short8*)(sh.st.ax[cur] + offA0 + rt * 512);
            #pragma unroll
            for (int ct = 0; ct < 2; ++ct) {
                accz[rt][ct] = __builtin_amdgcn_mfma_f32_16x16x32_bf16(fx, vz[ct], accz[rt][ct], 0, 0, 0);
                acch[rt][ct] = __builtin_amdgcn_mfma_f32_16x16x32_bf16(fx, vx[ct], acch[rt][ct], 0, 0, 0);
            }
        }
        asm volatile("" ::: "memory");
        __builtin_amdgcn_s_barrier();
        asm volatile("" ::: "memory");
    }

    gate_epilogue(sh.ep, tid, t0, n0, accz, acch, bz, bh0, aggA, aggB, abg, FWD);
}

// ---------------------------------------------------------------------------
// kernels
// ---------------------------------------------------------------------------
template<int FWD, int ABOUT>
__global__ __launch_bounds__(512, 4) void qrn_g5(
    const u16* __restrict__ xbg, const u16* __restrict__ qg,
    const u16* __restrict__ xqg, const u16* __restrict__ wt,
    const float* __restrict__ bz, const float* __restrict__ bh,
    float* __restrict__ aggA, float* __restrict__ aggB,
    u32* __restrict__ abg)
{
    __shared__ SharedP sh;
    const int tid  = threadIdx.x;
    const int bid  = (int)blockIdx.x;
    const int gidx = (bid & 7) * 128 + (bid >> 3);   // XCD-contiguous, bijective
    gemm_body(sh, tid, gidx >> 1, (gidx & 1) * GN,
              xbg, qg, xqg, wt, bz, bh, aggA, aggB, ABOUT ? abg : nullptr, FWD);
}

__global__ __launch_bounds__(512, 4) void qrn_gboth(
    const u16* __restrict__ xbg, const u16* __restrict__ qg,
    const u16* __restrict__ xqg,
    const u16* __restrict__ wtF, const u16* __restrict__ wtB,
    const float* __restrict__ bzf, const float* __restrict__ bhf,
    const float* __restrict__ bzb, const float* __restrict__ bhb,
    float* __restrict__ aggAf, float* __restrict__ aggBf,
    float* __restrict__ aggAb, float* __restrict__ aggBb,
    u32* __restrict__ abf, u32* __restrict__ abb)
{
    __shared__ SharedP sh;
    const int tid  = threadIdx.x;
    const int half = (int)blockIdx.x >> 10;       // 0=fwd, 1=bwd
    const int bid  = (int)blockIdx.x & 1023;
    const int gidx = (bid & 7) * 128 + (bid >> 3);
    gemm_body(sh, tid, gidx >> 1, (gidx & 1) * GN,
              xbg, qg, xqg,
              half ? wtB : wtF,
              half ? bzb : bzf, half ? bhb : bhf,
              half ? aggAb : aggAf, half ? aggBb : aggBf,
              half ? abb : abf, half ? 0 : 1);
}

template<int FWD>
__global__ __launch_bounds__(512, 4) void qrn_g0(
    const u16* __restrict__ xbg, const u16* __restrict__ wt,
    const float* __restrict__ bz, const float* __restrict__ bh0,
    float* __restrict__ aggA, float* __restrict__ aggB,
    u32* __restrict__ abg)
{
    __shared__ SharedP0 sh;
    const int tid  = threadIdx.x;
    const int bid  = (int)blockIdx.x;
    const int gidx = (bid & 7) * 128 + (bid >> 3);
    gemm0_body(sh, tid, gidx >> 1, (gidx & 1) * GN,
               xbg, wt, bz, bh0, aggA, aggB, abg, FWD);
}

__global__ __launch_bounds__(512, 4) void qrn_g0both(
    const u16* __restrict__ xbg,
    const u16* __restrict__ wtF, const u16* __restrict__ wtB,
    const float* __restrict__ bzf, const float* __restrict__ bh0f,
    const float* __restrict__ bzb, const float* __restrict__ bh0b,
    float* __restrict__ aggAf, float* __restrict__ aggBf,
    float* __restrict__ aggAb, float* __restrict__ aggBb,
    u32* __restrict__ abf, u32* __restrict__ abb)
{
    __shared__ SharedP0 sh;
    const int tid  = threadIdx.x;
    const int half = (int)blockIdx.x >> 10;
    const int bid  = (int)blockIdx.x & 1023;
    const int gidx = (bid & 7) * 128 + (bid >> 3);
    gemm0_body(sh, tid, gidx >> 1, (gidx & 1) * GN,
               xbg,
               half ? wtB : wtF,
               half ? bzb : bzf, half ? bh0b : bh0f,
               half ? aggAb : aggAf, half ? aggBb : aggBf,
               half ? abb : abf, half ? 0 : 1);
}

// ===========================================================================
// elementwise replay: ab holds (Aprod_t, hloc_t) packed bf16.
// ===========================================================================
__global__ __launch_bounds__(256) void replay2_fb(
    const u32* __restrict__ abf, const u32* __restrict__ abb,
    const float* __restrict__ hinif, const float* __restrict__ hinib,
    const u16* __restrict__ xb, u16* __restrict__ qout, u16* __restrict__ xq,
    int total8)
{
    for (int id = (int)blockIdx.x * 256 + (int)threadIdx.x; id < total8;
         id += (int)gridDim.x * 256) {
        int t  = id >> 5;
        int n0 = (id & 31) * 8;
        int c  = t >> 7;
        size_t o  = (size_t)t * D + n0;
        size_t hc = (size_t)c * D + n0;
        uint4 f0 = *(const uint4*)(abf + o);
        uint4 f1 = *(const uint4*)(abf + o + 4);
        uint4 g0 = *(const uint4*)(abb + o);
        uint4 g1 = *(const uint4*)(abb + o + 4);
        float4 hf0 = *(const float4*)(hinif + hc);
        float4 hf1 = *(const float4*)(hinif + hc + 4);
        float4 hb0 = *(const float4*)(hinib + hc);
        float4 hb1 = *(const float4*)(hinib + hc + 4);
        short8 xv = *(const short8*)(xb + o);
        u32 fa[8] = {f0.x, f0.y, f0.z, f0.w, f1.x, f1.y, f1.z, f1.w};
        u32 ga[8] = {g0.x, g0.y, g0.z, g0.w, g1.x, g1.y, g1.z, g1.w};
        float hfv[8] = {hf0.x, hf0.y, hf0.z, hf0.w, hf1.x, hf1.y, hf1.z, hf1.w};
        float hbv[8] = {hb0.x, hb0.y, hb0.z, hb0.w, hb1.x, hb1.y, hb1.z, hb1.w};
        short8 qs, xqs;
        #pragma unroll
        for (int i = 0; i < 8; ++i) {
            float hF = fmaf(b2f((u16)(fa[i] & 0xffff)), hfv[i], b2f((u16)(fa[i] >> 16)));
            float hB = fmaf(b2f((u16)(ga[i] & 0xffff)), hbv[i], b2f((u16)(ga[i] >> 16)));
            u16 qb = f2b(hF + hB);
            qs[i]  = (short)qb;
            xqs[i] = (short)f2b(b2f((u16)xv[i]) * b2f(qb));
        }
        *(short8*)(qout + o) = qs;
        *(short8*)(xq + o)   = xqs;
    }
}

__global__ __launch_bounds__(256) void replay2_f(
    const u32* __restrict__ abg, const float* __restrict__ hini,
    u16* __restrict__ qout, int total8)
{
    for (int id = (int)blockIdx.x * 256 + (int)threadIdx.x; id < total8;
         id += (int)gridDim.x * 256) {
        int t  = id >> 5;
        int n0 = (id & 31) * 8;
        int c  = t >> 7;
        size_t o  = (size_t)t * D + n0;
        size_t hc = (size_t)c * D + n0;
        uint4 f0 = *(const uint4*)(abg + o);
        uint4 f1 = *(const uint4*)(abg + o + 4);
        float4 hf0 = *(const float4*)(hini + hc);
        float4 hf1 = *(const float4*)(hini + hc + 4);
        u32 fa[8] = {f0.x, f0.y, f0.z, f0.w, f1.x, f1.y, f1.z, f1.w};
        float hfv[8] = {hf0.x, hf0.y, hf0.z, hf0.w, hf1.x, hf1.y, hf1.z, hf1.w};
        short8 qs;
        #pragma unroll
        for (int i = 0; i < 8; ++i) {
            float hF = fmaf(b2f((u16)(fa[i] & 0xffff)), hfv[i], b2f((u16)(fa[i] >> 16)));
            qs[i] = (short)f2b(hF);
        }
        *(short8*)(qout + o) = qs;
    }
}

__global__ __launch_bounds__(256) void replay2_b(
    const u32* __restrict__ abg, const float* __restrict__ hini,
    const u16* __restrict__ xb, u16* __restrict__ qout, u16* __restrict__ xq,
    int total8)
{
    for (int id = (int)blockIdx.x * 256 + (int)threadIdx.x; id < total8;
         id += (int)gridDim.x * 256) {
        int t  = id >> 5;
        int n0 = (id & 31) * 8;
        int c  = t >> 7;
        size_t o  = (size_t)t * D + n0;
        size_t hc = (size_t)c * D + n0;
        uint4 g0 = *(const uint4*)(abg + o);
        uint4 g1 = *(const uint4*)(abg + o + 4);
        float4 hb0 = *(const float4*)(hini + hc);
        float4 hb1 = *(const float4*)(hini + hc + 4);
        short8 qold = *(const short8*)(qout + o);
        short8 xv   = *(const short8*)(xb + o);
        u32 ga[8] = {g0.x, g0.y, g0.z, g0.w, g1.x, g1.y, g1.z, g1.w};
        float hbv[8] = {hb0.x, hb0.y, hb0.z, hb0.w, hb1.x, hb1.y, hb1.z, hb1.w};
        short8 qs, xqs;
        #pragma unroll
        for (int i = 0; i < 8; ++i) {
            float hB = fmaf(b2f((u16)(ga[i] & 0xffff)), hbv[i], b2f((u16)(ga[i] >> 16)));
            float qn = b2f((u16)qold[i]) + hB;
            u16 qb = f2b(qn);
            qs[i]  = (short)qb;
            xqs[i] = (short)f2b(b2f((u16)xv[i]) * b2f(qb));
        }
        *(short8*)(qout + o) = qs;
        *(short8*)(xq + o)   = xqs;
    }
}

// ---------------------------------------------------------------------------
// inter-chunk scans
// ---------------------------------------------------------------------------
__device__ __forceinline__ void scan_body(
    const float* aggA, const float* aggB, float* hinit, float* out_final,
    int fwd, int nch, int n, int tid)
{
    __shared__ float sA[256], sB[256];
    const int per = nch >> 8;
    float lA[4], lB[4];
    float A = 1.f, B = 0.f;
    for (int j = 0; j < per; ++j) {
        int pidx = tid * per + j;
        int c = fwd ? pidx : (nch - 1 - pidx);
        float a = aggA[(size_t)c * D + n];
        float b = aggB[(size_t)c * D + n];
        lA[j] = a; lB[j] = b;
        A = a * A;
        B = fmaf(a, B, b);
    }
    sA[tid] = A; sB[tid] = B;
    __syncthreads();
    for (int off = 1; off < 256; off <<= 1) {
        float pA = 1.f, pB = 0.f;
        if (tid >= off) { pA = sA[tid - off]; pB = sB[tid - off]; }
        __syncthreads();
        if (tid >= off) {
            float cA = sA[tid], cB = sB[tid];
            sA[tid] = pA * cA;
            sB[tid] = fmaf(cA, pB, cB);
        }
        __syncthreads();
    }
    float eB = (tid > 0) ? sB[tid - 1] : 0.f;
    for (int j = 0; j < per; ++j) {
        int pidx = tid * per + j;
        int c = fwd ? pidx : (nch - 1 - pidx);
        hinit[(size_t)c * D + n] = eB;
        eB = fmaf(lA[j], eB, lB[j]);
    }
    if (out_final != nullptr && tid == 0) out_final[n] = sB[255];
}

__global__ __launch_bounds__(256) void scan_p2_kernel(
    const float* __restrict__ aggA, const float* __restrict__ aggB,
    float* __restrict__ hinit, float* __restrict__ out_final, int fwd, int nch)
{
    scan_body(aggA, aggB, hinit, out_final, fwd, nch, blockIdx.x, threadIdx.x);
}

__global__ __launch_bounds__(256) void scan_dual_kernel(
    const float* __restrict__ aggAf, const float* __restrict__ aggBf, float* __restrict__ hf,
    const float* __restrict__ aggAb, const float* __restrict__ aggBb, float* __restrict__ hb,
    int nch)
{
    int b = blockIdx.x;
    int fwd = (b < D) ? 1 : 0;
    int n = fwd ? b : (b - D);
    scan_body(fwd ? aggAf : aggAb, fwd ? aggBf : aggBb,
              fwd ? hf : hb, nullptr, fwd, nch, n, threadIdx.x);
}

// ---------------------------------------------------------------------------
extern "C" void kernel_launch(void* const* d_in, const int* in_sizes, int n_in,
                              void* d_out, int out_size, void* d_ws, size_t ws_size,
                              hipStream_t stream) {
    const float* story    = (const float*)d_in[0];
    const float* question = (const float*)d_in[1];
    const float* Wz_f = (const float*)d_in[2];
    const float* bz_f = (const float*)d_in[3];
    const float* Wh_f = (const float*)d_in[4];
    const float* bh_f = (const float*)d_in[5];
    const float* Wz_b = (const float*)d_in[6];
    const float* bz_b = (const float*)d_in[7];
    const float* Wh_b = (const float*)d_in[8];
    const float* bh_b = (const float*)d_in[9];

    const int T    = in_sizes[0] / D;            // 65536
    const int NCH  = T / BT;                     // 512
    const size_t TD = (size_t)T * D;
    const size_t WTE = 5 * 3 * 65536;
    const int total8 = T * 32;                   // TD/8

    const size_t needF = 3 * TD * 2 + WTE * 2 + 2 * TD * 4
                       + (size_t)4 * NCH * D * 4 + 2 * D * 4 + 4096;
    const bool planF = ws_size >= needF;

    dim3 blk(256);
    dim3 gblk(512);                              // 8 waves, 64x32 wave tile
    dim3 gGrid((unsigned)(NCH * 2));             // 1024 (one dir, GN=128)
    dim3 g2Grid((unsigned)(NCH * 4));            // 2048 (both dirs)
    dim3 rGrid(2048);                            // replay grid-stride
    dim3 pGrid((unsigned)(TD / 8 / 256));

    if (planF) {
        u16* xb = (u16*)d_ws;
        u16* q  = xb + TD;
        u16* xq = q  + TD;
        u16* wt = xq + TD;
        u32* abf = (u32*)(wt + WTE);
        u32* abb = abf + TD;
        float* aggAf = (float*)(abb + TD);
        float* aggBf = aggAf + (size_t)NCH * D;
        float* aggAb = aggBf + (size_t)NCH * D;
        float* aggBb = aggAb + (size_t)NCH * D;
        float* bh0f  = aggBb + (size_t)NCH * D;
        float* bh0b  = bh0f + D;
        float* hinif = aggBf;                    // alias (safe)
        float* hinib = aggBb;                    // alias (safe)

        wtrans_kernel<<<dim3(5 * 3 * 65536 / 256), blk, 0, stream>>>(
            question, Wz_f, Wh_f, Wz_b, Wh_b, wt);
        bias0_kernel<<<dim3(2), blk, 0, stream>>>(
            question, Wh_f, Wh_b, bh_f, bh_b, bh0f, bh0b);
        prep0_kernel<<<pGrid, blk, 0, stream>>>(story, xb);

        for (int l = 0; l < 3; ++l) {
            const u16*   wtf = wt + (size_t)l * 3 * 65536;
            const float* bzf = bz_f + (size_t)l * D;
            const float* bhf = bh_f + (size_t)l * D;

            if (l == 2) {
                qrn_g5<1,0><<<gGrid, gblk, 0, stream>>>(
                    xb, q, xq, wtf, bzf, bhf, aggAf, aggBf, nullptr);
                scan_p2_kernel<<<dim3(D), blk, 0, stream>>>(
                    aggAf, aggBf, hinif, (float*)d_out, 1, NCH);
                break;
            }
            const u16*   wtb = wt + (size_t)(3 + l) * 3 * 65536;
            const float* bzb = bz_b + (size_t)l * D;
            const float* bhb = bh_b + (size_t)l * D;

            if (l == 0) {
                qrn_g0both<<<g2Grid, gblk, 0, stream>>>(
                    xb, wtf, wtb, bzf, bh0f, bzb, bh0b,
                    aggAf, aggBf, aggAb, aggBb, abf, abb);
            } else {
                qrn_gboth<<<g2Grid, gblk, 0, stream>>>(
                    xb, q, xq, wtf, wtb, bzf, bhf, bzb, bhb,
                    aggAf, aggBf, aggAb, aggBb, abf, abb);
            }
            scan_dual_kernel<<<dim3(2 * D), blk, 0, stream>>>(
                aggAf, aggBf, hinif, aggAb, aggBb, hinib, NCH);
            replay2_fb<<<rGrid, blk, 0, stream>>>(
                abf, abb, hinif, hinib, xb, q, xq, total8);
        }
    } else {
        // ---------------- plan P fallback ----------------
        u16* xb = (u16*)d_ws;
        u16* qA = xb + TD;
        u16* qB = qA + TD;
        u16* xq = qB + TD;
        u16* wt = xq + TD;
        u32*   ab   = (u32*)(wt + WTE);
        float* aggA = (float*)(ab + TD);
        float* aggB = aggA + (size_t)NCH * D;
        float* bh0f = aggB + (size_t)NCH * D;
        float* bh0b = bh0f + D;
        float* hini = aggB;

        wtrans_kernel<<<dim3(5 * 3 * 65536 / 256), blk, 0, stream>>>(
            question, Wz_f, Wh_f, Wz_b, Wh_b, wt);
        bias0_kernel<<<dim3(2), blk, 0, stream>>>(
            question, Wh_f, Wh_b, bh_f, bh_b, bh0f, bh0b);
        prep0_kernel<<<pGrid, blk, 0, stream>>>(story, xb);

        const u16* qcur  = qA;
        u16*       qnext = qB;

        for (int l = 0; l < 3; ++l) {
            const u16*   wtf = wt + (size_t)l * 3 * 65536;
            const float* bzf = bz_f + (size_t)l * D;
            const float* bhf = bh_f + (size_t)l * D;

            if (l == 2) {
                qrn_g5<1,0><<<gGrid, gblk, 0, stream>>>(
                    xb, qcur, xq, wtf, bzf, bhf, aggA, aggB, nullptr);
                scan_p2_kernel<<<dim3(D), blk, 0, stream>>>(
                    aggA, aggB, hini, (float*)d_out, 1, NCH);
                break;
            }
            const u16*   wtb = wt + (size_t)(3 + l) * 3 * 65536;
            const float* bzb = bz_b + (size_t)l * D;
            const float* bhb = bh_b + (size_t)l * D;

            if (l == 0) {
                qrn_g0<1><<<gGrid, gblk, 0, stream>>>(
                    xb, wtf, bzf, bh0f, aggA, aggB, ab);
                scan_p2_kernel<<<dim3(D), blk, 0, stream>>>(aggA, aggB, hini, nullptr, 1, NCH);
                replay2_f<<<rGrid, blk, 0, stream>>>(ab, hini, qnext, total8);

                qrn_g0<0><<<gGrid, gblk, 0, stream>>>(
                    xb, wtb, bzb, bh0b, aggA, aggB, ab);
                scan_p2_kernel<<<dim3(D), blk, 0, stream>>>(aggA, aggB, hini, nullptr, 0, NCH);
                replay2_b<<<rGrid, blk, 0, stream>>>(ab, hini, xb, qnext, xq, total8);
            } else {
                qrn_g5<1,1><<<gGrid, gblk, 0, stream>>>(
                    xb, qcur, xq, wtf, bzf, bhf, aggA, aggB, ab);
                scan_p2_kernel<<<dim3(D), blk, 0, stream>>>(aggA, aggB, hini, nullptr, 1, NCH);
                replay2_f<<<rGrid, blk, 0, stream>>>(ab, hini, qnext, total8);

                qrn_g5<0,1><<<gGrid, gblk, 0, stream>>>(
                    xb, qcur, xq, wtb, bzb, bhb, aggA, aggB, ab);
                scan_p2_kernel<<<dim3(D), blk, 0, stream>>>(aggA, aggB, hini, nullptr, 0, NCH);
                replay2_b<<<rGrid, blk, 0, stream>>>(ab, hini, xb, qnext, xq, total8);
            }
            const u16* ts = qcur; qcur = qnext; qnext = (u16*)ts;
        }
    }
}